// Round 15
// baseline (1201.514 us; speedup 1.0000x reference)
//
#include <hip/hip_runtime.h>
#include <math.h>

// ---------- types ----------
typedef unsigned short u16;
typedef __attribute__((ext_vector_type(8))) short short8;     // 8x16-bit raw (bf16 bits)
typedef __attribute__((ext_vector_type(8))) _Float16 half8;   // 8x fp16
typedef __attribute__((ext_vector_type(4))) float f32x4;

__device__ inline u16 f32_to_bf16_rne(float f){
    unsigned int u = __float_as_uint(f);
    unsigned int r = (u + 0x7FFFu + ((u >> 16) & 1u)) >> 16;
    return (u16)r;
}
__device__ inline float bf16_to_f32(u16 h){ return __uint_as_float(((unsigned int)h) << 16); }
__device__ inline u16 h2b(_Float16 h){ union { _Float16 f; u16 u; } x; x.f = h; return x.u; }

__device__ __forceinline__ void glds16(const void* g, void* l){
    __builtin_amdgcn_global_load_lds((const __attribute__((address_space(1))) void*)g,
                                     (__attribute__((address_space(3))) void*)l, 16, 0, 0);
}
#define WAIT_VM0()  { asm volatile("s_waitcnt vmcnt(0)" ::: "memory"); __builtin_amdgcn_sched_barrier(0); }
#define WAIT_VM3()  { asm volatile("s_waitcnt vmcnt(3)" ::: "memory"); __builtin_amdgcn_sched_barrier(0); }
#define WAIT_VM6()  { asm volatile("s_waitcnt vmcnt(6)" ::: "memory"); __builtin_amdgcn_sched_barrier(0); }
#define WAIT_LGKM0() { asm volatile("s_waitcnt lgkmcnt(0)" ::: "memory"); __builtin_amdgcn_sched_barrier(0); }
#define RAW_BAR()   { __builtin_amdgcn_s_barrier(); __builtin_amdgcn_sched_barrier(0); }

// ---------- constants ----------
#define TT 2048      // tokens
#define DD 2048      // model dim
#define SS 1024      // seq len
#define NH 16        // heads

#define EPI_F32     0
#define EPI_BF16    1
#define EPI_RES     2
#define EPI_SILUMUL 3
#define EPI_F16PAIR 4
#define EPI_QROPE   5
#define EPI_QKV     6

// =====================================================================
// Transpose-convert: W[K][N] f32 -> WT[N][K] 16-bit planes (zero-pad rows
// n >= Nsrc). PAIR=1: fp16 hi/lo planes; PAIR=0: bf16 single plane.
// grid: (Npad/64, K/64, E)
// =====================================================================
template<int PAIR>
__global__ __launch_bounds__(256) void cvtT_k(const float* __restrict__ W, long long wstr,
        u16* __restrict__ WTh, u16* __restrict__ WTl, long long tstr, int K, int Nsrc){
    __shared__ float L[64][65];
    int e = blockIdx.z;
    const float* Wp = W + (long long)e * wstr;
    int k0 = blockIdx.y * 64, n0 = blockIdx.x * 64;
    int tid = threadIdx.x;
#pragma unroll
    for (int it = 0; it < 4; ++it) {
        int r = (tid >> 4) + it * 16, cc = (tid & 15) * 4;
        int col = n0 + cc;
        float4 v = {0.f, 0.f, 0.f, 0.f};
        if (col + 3 < Nsrc) v = *(const float4*)(Wp + (long long)(k0 + r) * Nsrc + col);
        else {
            const float* p = Wp + (long long)(k0 + r) * Nsrc;
            float tmp[4] = {0.f, 0.f, 0.f, 0.f};
#pragma unroll
            for (int q2 = 0; q2 < 4; q2++) if (col + q2 < Nsrc) tmp[q2] = p[col + q2];
            v.x = tmp[0]; v.y = tmp[1]; v.z = tmp[2]; v.w = tmp[3];
        }
        L[r][cc] = v.x; L[r][cc+1] = v.y; L[r][cc+2] = v.z; L[r][cc+3] = v.w;
    }
    __syncthreads();
#pragma unroll
    for (int it = 0; it < 2; ++it) {
        int idx = it * 256 + tid; int n = idx >> 3, kc = (idx & 7) * 8;
        u16 hi[8], lo[8];
#pragma unroll
        for (int u = 0; u < 8; ++u) {
            float v = L[kc + u][n];
            if (PAIR) { _Float16 h = (_Float16)v; hi[u] = h2b(h); lo[u] = h2b((_Float16)(v - (float)h)); }
            else hi[u] = f32_to_bf16_rne(v);
        }
        long long o = (long long)e * tstr + (long long)(n0 + n) * K + k0 + kc;
        *(short8*)(WTh + o) = *(short8*)hi;
        if (PAIR) *(short8*)(WTl + o) = *(short8*)lo;
    }
}

// =====================================================================
// PREC 64x128 MFMA GEMM (split-fp16, 3 MFMA/term), 3-deep glds pipeline
// (72KB LDS, counted vmcnt(6): one 6-load tile in flight across the
// barrier). Waves 2x2, wave tile 32x64, acc 2x4. Epilogues:
//   EPI_RES:     f32 C0 = acc + aux
//   EPI_F16PAIR: fp16 hi/lo pair to C0/C1
//   EPI_QKV:     n0<3072 -> roped q pair (ldc=3072); else f32 kv into aux
// Full-M assumed (M=2048, grid covers exactly). gridDim.x % 8 == 0.
// =====================================================================
template<int EPI>
__global__ __launch_bounds__(256) void gemmp3_k(
    const u16* __restrict__ A0, const u16* __restrict__ A1, int lda,
    const u16* __restrict__ BTh, const u16* __restrict__ BTl,
    int M, int N, int K,
    void* C0, void* C1, int ldc, const void* aux,
    const float* __restrict__ cosT, const float* __restrict__ sinT)
{
    __shared__ u16 AsH[3][2048];   // 64 rows x 64B
    __shared__ u16 AsL[3][2048];
    __shared__ u16 BsH[3][4096];   // 128 rows x 64B
    __shared__ u16 BsL[3][4096];

    int tid  = threadIdx.x;
    int lane = tid & 63;
    int wv   = tid >> 6;
    int wm = (wv >> 1) * 32, wn = (wv & 1) * 64;

    int Lid = blockIdx.y * gridDim.x + blockIdx.x;
    int jj  = Lid >> 3;
    int yb  = jj % gridDim.y;
    int nb  = (Lid & 7) + ((jj / gridDim.y) << 3);
    int n0 = nb * 128;
    if (n0 >= N) return;
    int m0 = yb * 64;
    if (m0 >= M) return;

    // per-lane glds source offsets (fixed across K)
    int rr = tid >> 2;                 // 0..63
    int sl4 = tid & 3;
    int sA = sl4 ^ ((rr >> 1) & 3);
    int rb1 = rr + 64;
    int sB1 = sl4 ^ ((rb1 >> 1) & 3);
    long long aro = (long long)(m0 + rr) * lda + sA * 8;
    long long bro0 = (long long)(n0 + rr) * K + sA * 8;
    long long bro1 = (long long)(n0 + rb1) * K + sB1 * 8;

    f32x4 acc[2][4];
#pragma unroll
    for (int i = 0; i < 2; i++)
#pragma unroll
        for (int j = 0; j < 4; j++) { f32x4 z = {0.f,0.f,0.f,0.f}; acc[i][j] = z; }

#define STGP(PB, KT)                                                        \
    {                                                                       \
        glds16(BTh + bro0 + (KT), (char*)&BsH[PB][0] + wv * 1024);          \
        glds16(BTh + bro1 + (KT), (char*)&BsH[PB][0] + 4096 + wv * 1024);   \
        glds16(BTl + bro0 + (KT), (char*)&BsL[PB][0] + wv * 1024);          \
        glds16(BTl + bro1 + (KT), (char*)&BsL[PB][0] + 4096 + wv * 1024);   \
        glds16(A0 + aro + (KT),  (char*)&AsH[PB][0] + wv * 1024);           \
        glds16(A1 + aro + (KT),  (char*)&AsL[PB][0] + wv * 1024);           \
    }

    int nst = K >> 5;
    STGP(0, 0);
    if (nst > 1) STGP(1, 32);
    for (int t = 0; t < nst; ++t) {
        if (t + 1 < nst) { WAIT_VM6(); }   // tile t landed; tile t+1 (6 loads) in flight
        else            { WAIT_VM0(); }
        RAW_BAR();
        if (t + 2 < nst) { int p2 = (t + 2) % 3; STGP(p2, (t + 2) * 32); }
        int pb = t % 3;
        half8 ah[2], al[2];
#pragma unroll
        for (int i = 0; i < 2; i++) {
            int ra = wm + i * 16 + (lane & 15);
            int off = ra * 64 + 16 * ((lane >> 4) ^ ((ra >> 1) & 3));
            ah[i] = *(const half8*)((const char*)&AsH[pb][0] + off);
            al[i] = *(const half8*)((const char*)&AsL[pb][0] + off);
        }
#pragma unroll
        for (int j = 0; j < 4; j++) {
            int rb = wn + j * 16 + (lane & 15);
            int off = rb * 64 + 16 * ((lane >> 4) ^ ((rb >> 1) & 3));
            half8 bh = *(const half8*)((const char*)&BsH[pb][0] + off);
            half8 bl = *(const half8*)((const char*)&BsL[pb][0] + off);
#pragma unroll
            for (int i = 0; i < 2; i++) {
                acc[i][j] = __builtin_amdgcn_mfma_f32_16x16x32_f16(ah[i], bh, acc[i][j], 0, 0, 0);
                acc[i][j] = __builtin_amdgcn_mfma_f32_16x16x32_f16(ah[i], bl, acc[i][j], 0, 0, 0);
                acc[i][j] = __builtin_amdgcn_mfma_f32_16x16x32_f16(al[i], bh, acc[i][j], 0, 0, 0);
            }
        }
    }
#undef STGP

    // ---- epilogue ----
    if (EPI == EPI_QKV && n0 >= 3072) {
        // kv region: cols 3072..3647 -> f32 kv[rr][col-3072]
        float* kvo = (float*)aux;
#pragma unroll
        for (int i = 0; i < 2; i++) {
            int rr0 = m0 + wm + i * 16 + ((lane >> 4) << 2);
#pragma unroll
            for (int j = 0; j < 4; j++) {
                int col = n0 + wn + j * 16 + (lane & 15);
                if (col >= 3648) continue;
#pragma unroll
                for (int r = 0; r < 4; r++) {
                    int rr2 = rr0 + r;
                    kvo[(long long)rr2 * 576 + (col - 3072)] = acc[i][j][r];
                }
            }
        }
    } else if (EPI == EPI_QKV) {
        // roped q pair
#pragma unroll
        for (int i = 0; i < 2; i++) {
            int rr0 = m0 + wm + i * 16 + ((lane >> 4) << 2);
#pragma unroll
            for (int j = 0; j < 4; j++) {
                int col = n0 + wn + j * 16 + (lane & 15);
                int hd = col % 192;
#pragma unroll
                for (int r = 0; r < 4; r++) {
                    int rr2 = rr0 + r;
                    float v = acc[i][j][r];
                    float pv = __shfl_xor(v, 1);
                    float outv = v;
                    if (hd >= 128) {
                        int s = rr2 & (SS - 1);
                        int pi2 = (hd - 128) >> 1;
                        float cc_ = cosT[s * 32 + pi2], sn_ = sinT[s * 32 + pi2];
                        bool odd = col & 1;
                        float a0 = odd ? pv : v, a1 = odd ? v : pv;
                        outv = odd ? (a0 * sn_ + a1 * cc_) : (a0 * cc_ - a1 * sn_);
                    }
                    long long cidx = (long long)rr2 * ldc + col;
                    _Float16 hh = (_Float16)outv;
                    ((u16*)C0)[cidx] = h2b(hh);
                    ((u16*)C1)[cidx] = h2b((_Float16)(outv - (float)hh));
                }
            }
        }
    } else {
#pragma unroll
        for (int i = 0; i < 2; i++) {
            int rr0 = m0 + wm + i * 16 + ((lane >> 4) << 2);
#pragma unroll
            for (int j = 0; j < 4; j++) {
                int col = n0 + wn + j * 16 + (lane & 15);
                if (col >= N) continue;
#pragma unroll
                for (int r = 0; r < 4; r++) {
                    int rr2 = rr0 + r;
                    long long cidx = (long long)rr2 * ldc + col;
                    float v = acc[i][j][r];
                    if (EPI == EPI_RES) {
                        ((float*)C0)[cidx] = v + ((const float*)aux)[cidx];
                    } else { // EPI_F16PAIR
                        _Float16 hh = (_Float16)v;
                        ((u16*)C0)[cidx] = h2b(hh);
                        ((u16*)C1)[cidx] = h2b((_Float16)(v - (float)hh));
                    }
                }
            }
        }
    }
}

// =====================================================================
// bf16 64x128 MFMA GEMM (4 waves as 2x2, wave tile 32x64, acc 2x4),
// 3-deep glds pipeline (36KB LDS, counted vmcnt(3)).
// =====================================================================
template<int EPI, bool GATHER>
__global__ __launch_bounds__(256) void gemm3_k(
    const u16* __restrict__ A0, int lda,
    const u16* __restrict__ BTh, long long btstr,
    int M, int N, int K,
    const int* offs, const int* cnt, const int* gather, int ebase,
    void* C0, void* C1, int ldc,
    const void* aux, int zsplit)
{
    __shared__ u16 As[3][2048];   // 64 rows x 64B
    __shared__ u16 Bs[3][4096];   // 128 rows x 64B

    int tid  = threadIdx.x;
    int lane = tid & 63;
    int wv   = tid >> 6;
    int wm = (wv >> 1) * 32, wn = (wv & 1) * 64;

    int Lid = blockIdx.y * gridDim.x + blockIdx.x;
    int jj  = Lid >> 3;
    int yb  = jj % gridDim.y;
    int nb  = (Lid & 7) + ((jj / gridDim.y) << 3);
    int n0 = nb * 128;
    if (n0 >= N) return;

    int zz   = blockIdx.z;
    int e    = ebase + ((zsplit > 0 && zz >= zsplit) ? (zz - zsplit) : zz);
    int base = offs ? offs[e] : 0;
    int mc   = cnt ? cnt[e] : M;
    int m0   = yb * 64;
    if (m0 >= mc) return;
    const u16* Bh = BTh + (long long)zz * btstr;
    void* Cw = (zsplit > 0 && zz >= zsplit) ? C1 : C0;

    int rr = tid >> 2;                 // 0..63
    int sl4 = tid & 3;
    int sA = sl4 ^ ((rr >> 1) & 3);
    long long bro0, bro1, aro0;
    {
        int rb1 = rr + 64;
        int sB1 = sl4 ^ ((rb1 >> 1) & 3);
        bro0 = (long long)(n0 + rr) * K + sA * 8;
        bro1 = (long long)(n0 + rb1) * K + sB1 * 8;
        int ar = m0 + rr; ar = (ar < mc) ? ar : (mc - 1);   // clamp; garbage masked at epilogue
        long long ga = GATHER ? (long long)gather[base + ar] : (long long)(base + ar);
        aro0 = ga * (long long)lda + sA * 8;
    }

    f32x4 acc[2][4];
#pragma unroll
    for (int i = 0; i < 2; i++)
#pragma unroll
        for (int j = 0; j < 4; j++) { f32x4 z = {0.f,0.f,0.f,0.f}; acc[i][j] = z; }

#define STG3(PB, KT)                                                        \
    {                                                                       \
        glds16(Bh + bro0 + (KT), (char*)&Bs[PB][0] + wv * 1024);            \
        glds16(Bh + bro1 + (KT), (char*)&Bs[PB][0] + 4096 + wv * 1024);     \
        glds16(A0 + aro0 + (KT), (char*)&As[PB][0] + wv * 1024);            \
    }

    int nst = K >> 5;
    STG3(0, 0);
    if (nst > 1) STG3(1, 32);
    for (int t = 0; t < nst; ++t) {
        if (t + 1 < nst) { WAIT_VM3(); }
        else            { WAIT_VM0(); }
        RAW_BAR();
        if (t + 2 < nst) { int p2 = (t + 2) % 3; STG3(p2, (t + 2) * 32); }
        int pb = t % 3;
        short8 af[2];
#pragma unroll
        for (int i = 0; i < 2; i++) {
            int ra = wm + i * 16 + (lane & 15);
            af[i] = *(const short8*)((const char*)&As[pb][0] + ra * 64 + 16 * ((lane >> 4) ^ ((ra >> 1) & 3)));
        }
#pragma unroll
        for (int j = 0; j < 4; j++) {
            int rb = wn + j * 16 + (lane & 15);
            short8 bfr = *(const short8*)((const char*)&Bs[pb][0] + rb * 64 + 16 * ((lane >> 4) ^ ((rb >> 1) & 3)));
#pragma unroll
            for (int i = 0; i < 2; i++)
                acc[i][j] = __builtin_amdgcn_mfma_f32_16x16x32_bf16(af[i], bfr, acc[i][j], 0, 0, 0);
        }
    }
#undef STG3

    // ---- epilogue ----
#pragma unroll
    for (int i = 0; i < 2; i++) {
        int rbase = m0 + wm + i * 16 + ((lane >> 4) << 2);
#pragma unroll
        for (int j = 0; j < 4; j++) {
            int col = n0 + wn + j * 16 + (lane & 15);
            if (col >= N) continue;
#pragma unroll
            for (int r = 0; r < 4; r++) {
                int rr2 = rbase + r;
                if (rr2 >= mc) continue;
                long long cidx = (long long)(base + rr2) * ldc + col;
                float v = acc[i][j][r];
                if (EPI == EPI_BF16) ((u16*)Cw)[cidx] = f32_to_bf16_rne(v);
                else { // EPI_SILUMUL
                    float h1v = bf16_to_f32(((const u16*)aux)[cidx]);
                    float g = h1v / (1.f + __expf(-h1v)) * v;
                    ((u16*)C0)[cidx] = f32_to_bf16_rne(g);
                }
            }
        }
    }
}

// =====================================================================
// silumul: g = silu(g) * h3 elementwise (bf16), n elements (mult of 8)
// =====================================================================
__global__ __launch_bounds__(256) void silumul_k(u16* __restrict__ g, const u16* __restrict__ h3,
                                                 long long n){
    long long i = ((long long)blockIdx.x * 256 + threadIdx.x) * 8;
    if (i >= n) return;
    short8 a = *(const short8*)(g + i);
    short8 b = *(const short8*)(h3 + i);
    u16 o[8];
#pragma unroll
    for (int u = 0; u < 8; ++u) {
        float x = bf16_to_f32((u16)a[u]);
        float y = bf16_to_f32((u16)b[u]);
        o[u] = f32_to_bf16_rne(x / (1.f + __expf(-x)) * y);
    }
    *(short8*)(g + i) = *(short8*)o;
}

// =====================================================================
// cos/sin table: [S][32]
// =====================================================================
__global__ void costab_k(const int* sp, float* ct, float* st){
    int idx = blockIdx.x * 256 + threadIdx.x;
    if (idx >= SS * 32) return;
    int i = idx & 31, s = idx >> 5;
    float inv = powf(10000.0f, -(float)i / 32.0f);
    float a = (float)(sp[0] + s) * inv;
    ct[idx] = cosf(a);
    st[idx] = sinf(a);
}

// =====================================================================
// rmsnorm: row of 2048 f32 -> MODE 0: fp16 hi/lo planes; MODE 1: bf16
// =====================================================================
template<int MODE>
__global__ __launch_bounds__(256) void rms_k(const float* __restrict__ x, const float* __restrict__ w,
                                             u16* o0, u16* o1){
    int t = blockIdx.x, tid = threadIdx.x;
    const float* row = x + (long long)t * DD;
    float4 v0 = *(const float4*)(row + tid * 4);
    float4 v1 = *(const float4*)(row + 1024 + tid * 4);
    float ss = v0.x*v0.x + v0.y*v0.y + v0.z*v0.z + v0.w*v0.w
             + v1.x*v1.x + v1.y*v1.y + v1.z*v1.z + v1.w*v1.w;
#pragma unroll
    for (int d = 1; d < 64; d <<= 1) ss += __shfl_xor(ss, d, 64);
    __shared__ float red[4];
    if ((tid & 63) == 0) red[tid >> 6] = ss;
    __syncthreads();
    float sc = rsqrtf((red[0] + red[1] + red[2] + red[3]) / (float)DD + 1e-6f);
    float a[8];
    a[0]=v0.x; a[1]=v0.y; a[2]=v0.z; a[3]=v0.w; a[4]=v1.x; a[5]=v1.y; a[6]=v1.z; a[7]=v1.w;
#pragma unroll
    for (int q2 = 0; q2 < 8; q2++) {
        int d = (q2 < 4) ? (tid * 4 + q2) : (1024 + tid * 4 + (q2 - 4));
        float y = a[q2] * sc * w[d];
        if (MODE == 0) {
            _Float16 hh = (_Float16)y;
            o0[(long long)t * DD + d] = h2b(hh);
            o1[(long long)t * DD + d] = h2b((_Float16)(y - (float)hh));
        } else {
            o0[(long long)t * DD + d] = f32_to_bf16_rne(y);
        }
    }
}

// =====================================================================
// kvprep: rmsnorm(kv[:,:512]) -> fp16 pair; rope(kv[:,512:576]) -> fp16 pair
// =====================================================================
__global__ __launch_bounds__(256) void kvprep_k(const float* __restrict__ kv, const float* __restrict__ kw,
    const float* __restrict__ ct, const float* __restrict__ st,
    u16* lath, u16* latl, u16* kpeh, u16* kpel){
    int t = blockIdx.x, tid = threadIdx.x;
    const float* row = kv + (long long)t * 576;
    float x0 = row[tid], x1 = row[256 + tid];
    float ss = x0 * x0 + x1 * x1;
#pragma unroll
    for (int d = 1; d < 64; d <<= 1) ss += __shfl_xor(ss, d, 64);
    __shared__ float red[4];
    if ((tid & 63) == 0) red[tid >> 6] = ss;
    __syncthreads();
    float sc = rsqrtf((red[0] + red[1] + red[2] + red[3]) / 512.f + 1e-6f);
    float y0 = x0 * sc * kw[tid], y1 = x1 * sc * kw[256 + tid];
    _Float16 h0 = (_Float16)y0, h1 = (_Float16)y1;
    lath[(long long)t * 512 + tid] = h2b(h0);
    latl[(long long)t * 512 + tid] = h2b((_Float16)(y0 - (float)h0));
    lath[(long long)t * 512 + 256 + tid] = h2b(h1);
    latl[(long long)t * 512 + 256 + tid] = h2b((_Float16)(y1 - (float)h1));
    if (tid < 32) {
        int s = t & (SS - 1);
        float a0 = row[512 + 2 * tid], a1 = row[513 + 2 * tid];
        float c = ct[s * 32 + tid], sn = st[s * 32 + tid];
        float r0 = a0 * c - a1 * sn, r1 = a0 * sn + a1 * c;
        _Float16 p0 = (_Float16)r0, p1 = (_Float16)r1;
        kpeh[(long long)t * 64 + 2 * tid]     = h2b(p0);
        kpel[(long long)t * 64 + 2 * tid]     = h2b((_Float16)(r0 - (float)p0));
        kpeh[(long long)t * 64 + 2 * tid + 1] = h2b(p1);
        kpel[(long long)t * 64 + 2 * tid + 1] = h2b((_Float16)(r1 - (float)p1));
    }
}

// =====================================================================
// vtprep: v^T planes [BH][128][S] from kvb planes (z selects plane)
// =====================================================================
__global__ __launch_bounds__(256) void vtprep_k(const u16* __restrict__ kvbh, const u16* __restrict__ kvbl,
                                                u16* vth, u16* vtl){
    __shared__ u16 L[64][136];
    int bh = blockIdx.x, st = blockIdx.y, pl = blockIdx.z;
    const u16* src = pl ? kvbl : kvbh;
    u16* dst = pl ? vtl : vth;
    int b = bh >> 4, hh = bh & 15;
    int tid = threadIdx.x;
#pragma unroll
    for (int it = 0; it < 4; ++it) {
        int idx = it * 256 + tid; int sl = idx >> 4, dc = idx & 15;
        long long t = (long long)b * SS + st * 64 + sl;
        *(short8*)&L[sl][dc * 8] = *(const short8*)(src + t * 4096 + hh * 256 + 128 + dc * 8);
    }
    __syncthreads();
#pragma unroll
    for (int it = 0; it < 4; ++it) {
        int idx = it * 256 + tid; int d = idx >> 3, sc = idx & 7;
        short8 v;
#pragma unroll
        for (int u = 0; u < 8; u++) v[u] = (short)L[sc * 8 + u][d];
        *(short8*)(dst + ((long long)bh * 128 + d) * SS + st * 64 + sc * 8) = v;
    }
}

// =====================================================================
// Flash attention, split-fp16, causal. T14 async-staged K/V (reg prefetch
// overlaps compute), per-CU complementary-qi pairing for load balance.
// =====================================================================
__global__ __launch_bounds__(256) void attn_k(
    const u16* __restrict__ qh_, const u16* __restrict__ ql_,
    const u16* __restrict__ kvbh, const u16* __restrict__ kvbl,
    const u16* __restrict__ kpeh, const u16* __restrict__ kpel,
    const u16* __restrict__ vth, const u16* __restrict__ vtl,
    u16* ohi, u16* olo)
{
    __shared__ u16 KsH[32][200], KsL[32][200];
    __shared__ u16 VsH[128][40], VsL[128][40];
    __shared__ u16 PlH[4][16][40], PlL[4][16][40];
    int bx = blockIdx.x, bh = blockIdx.y;
    int qi = (bh & 16) ? bx : (15 - bx);
    int b = bh >> 4, h = bh & 15;
    int tid = threadIdx.x, lane = tid & 63, wv = tid >> 6;
    int q0 = qi * 64;
    const u16* vbh = vth + (long long)bh * 128 * SS;
    const u16* vbl = vtl + (long long)bh * 128 * SS;

    half8 qh[6], ql[6];
    {
        int row = q0 + wv * 16 + (lane & 15);
        const u16* ph = qh_ + (long long)(b * SS + row) * 3072 + h * 192 + (lane >> 4) * 8;
        const u16* pl = ql_ + (long long)(b * SS + row) * 3072 + h * 192 + (lane >> 4) * 8;
#pragma unroll
        for (int ks = 0; ks < 6; ks++) {
            qh[ks] = *(const half8*)(ph + ks * 32);
            ql[ks] = *(const half8*)(pl + ks * 32);
        }
    }
    float mrun[4], lrun[4];
    f32x4 oacc[8];
#pragma unroll
    for (int r = 0; r < 4; r++) { mrun[r] = -1e30f; lrun[r] = 0.f; }
#pragma unroll
    for (int f = 0; f < 8; f++) { f32x4 z = {0.f,0.f,0.f,0.f}; oacc[f] = z; }
    const float scale = 0.07216878364870322f; // 1/sqrt(192)

    short8 kh0, kh1, kh2, kl0, kl1, kl2, vh0, vh1, vl0, vl1;
    int kr0 = tid / 24 + 0,  kc0 = tid % 24;
    int kr1 = (256 + tid) / 24, kc1 = (256 + tid) % 24;
    int kr2 = (512 + tid) / 24, kc2 = (512 + tid) % 24;
    int vr0 = tid >> 2, vc0 = tid & 3;
    int vr1 = (256 + tid) >> 2, vc1 = vc0;

#define ALOAD(T0)                                                                   \
    {                                                                               \
        long long tg0 = (long long)b * SS + (T0);                                   \
        if (kc0 < 16) { kh0 = *(const short8*)(kvbh + (tg0 + kr0) * 4096 + h * 256 + kc0 * 8); \
                        kl0 = *(const short8*)(kvbl + (tg0 + kr0) * 4096 + h * 256 + kc0 * 8); } \
        else          { kh0 = *(const short8*)(kpeh + (tg0 + kr0) * 64 + (kc0 - 16) * 8);      \
                        kl0 = *(const short8*)(kpel + (tg0 + kr0) * 64 + (kc0 - 16) * 8); }    \
        if (kc1 < 16) { kh1 = *(const short8*)(kvbh + (tg0 + kr1) * 4096 + h * 256 + kc1 * 8); \
                        kl1 = *(const short8*)(kvbl + (tg0 + kr1) * 4096 + h * 256 + kc1 * 8); } \
        else          { kh1 = *(const short8*)(kpeh + (tg0 + kr1) * 64 + (kc1 - 16) * 8);      \
                        kl1 = *(const short8*)(kpel + (tg0 + kr1) * 64 + (kc1 - 16) * 8); }    \
        if (kc2 < 16) { kh2 = *(const short8*)(kvbh + (tg0 + kr2) * 4096 + h * 256 + kc2 * 8); \
                        kl2 = *(const short8*)(kvbl + (tg0 + kr2) * 4096 + h * 256 + kc2 * 8); } \
        else          { kh2 = *(const short8*)(kpeh + (tg0 + kr2) * 64 + (kc2 - 16) * 8);      \
                        kl2 = *(const short8*)(kpel + (tg0 + kr2) * 64 + (kc2 - 16) * 8); }    \
        vh0 = *(const short8*)(vbh + (long long)vr0 * SS + (T0) + vc0 * 8);         \
        vl0 = *(const short8*)(vbl + (long long)vr0 * SS + (T0) + vc0 * 8);         \
        vh1 = *(const short8*)(vbh + (long long)vr1 * SS + (T0) + vc1 * 8);         \
        vl1 = *(const short8*)(vbl + (long long)vr1 * SS + (T0) + vc1 * 8);         \
    }

    int ntile = 2 * qi + 2;
    ALOAD(0);
    for (int ti = 0; ti < ntile; ++ti) {
        int t0 = ti * 32;
        WAIT_VM0();
        RAW_BAR();
        *(short8*)&KsH[kr0][kc0 * 8] = kh0; *(short8*)&KsL[kr0][kc0 * 8] = kl0;
        *(short8*)&KsH[kr1][kc1 * 8] = kh1; *(short8*)&KsL[kr1][kc1 * 8] = kl1;
        *(short8*)&KsH[kr2][kc2 * 8] = kh2; *(short8*)&KsL[kr2][kc2 * 8] = kl2;
        *(short8*)&VsH[vr0][vc0 * 8] = vh0; *(short8*)&VsL[vr0][vc0 * 8] = vl0;
        *(short8*)&VsH[vr1][vc1 * 8] = vh1; *(short8*)&VsL[vr1][vc1 * 8] = vl1;
        WAIT_LGKM0();
        RAW_BAR();
        if (ti + 1 < ntile) ALOAD(t0 + 32);
        f32x4 s[2];
#pragma unroll
        for (int nt = 0; nt < 2; ++nt) {
            f32x4 a = {0.f,0.f,0.f,0.f};
#pragma unroll
            for (int ks = 0; ks < 6; ++ks) {
                half8 kh = *(const half8*)&KsH[nt * 16 + (lane & 15)][ks * 32 + (lane >> 4) * 8];
                half8 kl = *(const half8*)&KsL[nt * 16 + (lane & 15)][ks * 32 + (lane >> 4) * 8];
                a = __builtin_amdgcn_mfma_f32_16x16x32_f16(qh[ks], kh, a, 0, 0, 0);
                a = __builtin_amdgcn_mfma_f32_16x16x32_f16(qh[ks], kl, a, 0, 0, 0);
                a = __builtin_amdgcn_mfma_f32_16x16x32_f16(ql[ks], kh, a, 0, 0, 0);
            }
            s[nt] = a;
        }
#pragma unroll
        for (int nt = 0; nt < 2; ++nt)
#pragma unroll
            for (int r = 0; r < 4; ++r) {
                float v = s[nt][r] * scale;
                if (ti >= 2 * qi) {
                    int t = t0 + nt * 16 + (lane & 15);
                    int sq = q0 + wv * 16 + (lane >> 4) * 4 + r;
                    if (t > sq) v = -1e30f;
                }
                s[nt][r] = v;
            }
        float corr[4];
#pragma unroll
        for (int r = 0; r < 4; ++r) {
            float m = fmaxf(s[0][r], s[1][r]);
#pragma unroll
            for (int d = 1; d < 16; d <<= 1) m = fmaxf(m, __shfl_xor(m, d, 64));
            float mn = fmaxf(mrun[r], m);
            corr[r] = __expf(mrun[r] - mn);
            mrun[r] = mn;
        }
        float rs[4] = {0.f, 0.f, 0.f, 0.f};
#pragma unroll
        for (int nt = 0; nt < 2; ++nt)
#pragma unroll
            for (int r = 0; r < 4; ++r) {
                float p = __expf(s[nt][r] - mrun[r]);
                s[nt][r] = p;
                rs[r] += p;
            }
#pragma unroll
        for (int r = 0; r < 4; ++r) {
            float tsum = rs[r];
#pragma unroll
            for (int d = 1; d < 16; d <<= 1) tsum += __shfl_xor(tsum, d, 64);
            lrun[r] = lrun[r] * corr[r] + tsum;
        }
#pragma unroll
        for (int f = 0; f < 8; f++)
#pragma unroll
            for (int r = 0; r < 4; r++) oacc[f][r] *= corr[r];
#pragma unroll
        for (int nt = 0; nt < 2; ++nt)
#pragma unroll
            for (int r = 0; r < 4; ++r) {
                float p = s[nt][r];
                _Float16 ph = (_Float16)p;
                PlH[wv][(lane >> 4) * 4 + r][nt * 16 + (lane & 15)] = h2b(ph);
                PlL[wv][(lane >> 4) * 4 + r][nt * 16 + (lane & 15)] = h2b((_Float16)(p - (float)ph));
            }
        half8 pfh = *(const half8*)&PlH[wv][lane & 15][(lane >> 4) * 8];
        half8 pfl = *(const half8*)&PlL[wv][lane & 15][(lane >> 4) * 8];
#pragma unroll
        for (int f = 0; f < 8; ++f) {
            half8 vh = *(const half8*)&VsH[f * 16 + (lane & 15)][(lane >> 4) * 8];
            half8 vl = *(const half8*)&VsL[f * 16 + (lane & 15)][(lane >> 4) * 8];
            oacc[f] = __builtin_amdgcn_mfma_f32_16x16x32_f16(pfh, vh, oacc[f], 0, 0, 0);
            oacc[f] = __builtin_amdgcn_mfma_f32_16x16x32_f16(pfh, vl, oacc[f], 0, 0, 0);
            oacc[f] = __builtin_amdgcn_mfma_f32_16x16x32_f16(pfl, vh, oacc[f], 0, 0, 0);
        }
    }
#undef ALOAD
#pragma unroll
    for (int f = 0; f < 8; ++f)
#pragma unroll
        for (int r = 0; r < 4; ++r) {
            int sq = q0 + wv * 16 + (lane >> 4) * 4 + r;
            float v = oacc[f][r] / lrun[r];
            _Float16 hh = (_Float16)v;
            long long o = ((long long)(b * SS + sq)) * 2048 + h * 128 + f * 16 + (lane & 15);
            ohi[o] = h2b(hh);
            olo[o] = h2b((_Float16)(v - (float)hh));
        }
}

// =====================================================================
// gate: per-token f32 rmsnorm + 12 dots + sigmoid + top-4 (wave per token)
// =====================================================================
__global__ __launch_bounds__(256) void gate_k(const float* __restrict__ first,
    const float* __restrict__ nw, const float* __restrict__ gw, const float* __restrict__ gb,
    int* topi, float* wgt){
    int wv = threadIdx.x >> 6, lane = threadIdx.x & 63;
    int t = blockIdx.x * 4 + wv;
    const float* row = first + (long long)t * DD;
    float rv[32];
    float ss = 0.f;
#pragma unroll
    for (int it = 0; it < 32; ++it) {
        float v = row[it * 64 + lane];
        rv[it] = v;
        ss += v * v;
    }
#pragma unroll
    for (int d = 1; d < 64; d <<= 1) ss += __shfl_xor(ss, d, 64);
    float sc = rsqrtf(ss / (float)DD + 1e-6f);
    float acc[12];
#pragma unroll
    for (int e = 0; e < 12; e++) acc[e] = 0.f;
#pragma unroll
    for (int it = 0; it < 32; ++it) {
        int i = it * 64 + lane;
        float v = rv[it] * sc * nw[i];
        const float* g = gw + (long long)i * 12;
        float4 g0 = *(const float4*)g;
        float4 g1 = *(const float4*)(g + 4);
        float4 g2 = *(const float4*)(g + 8);
        acc[0] += v * g0.x; acc[1] += v * g0.y; acc[2]  += v * g0.z; acc[3]  += v * g0.w;
        acc[4] += v * g1.x; acc[5] += v * g1.y; acc[6]  += v * g1.z; acc[7]  += v * g1.w;
        acc[8] += v * g2.x; acc[9] += v * g2.y; acc[10] += v * g2.z; acc[11] += v * g2.w;
    }
#pragma unroll
    for (int e = 0; e < 12; e++)
#pragma unroll
        for (int d = 1; d < 64; d <<= 1) acc[e] += __shfl_xor(acc[e], d, 64);
    if (lane == 0) {
        float s[12], rank[12];
#pragma unroll
        for (int e = 0; e < 12; e++) { s[e] = 1.f / (1.f + expf(-acc[e])); rank[e] = s[e] + gb[e]; }
        int sel[4]; float wv4[4]; float wsum = 0.f;
#pragma unroll
        for (int k = 0; k < 4; k++) {
            int bi = 0; float bv = -1e30f;
#pragma unroll
            for (int e = 0; e < 12; e++) if (rank[e] > bv) { bv = rank[e]; bi = e; }
            sel[k] = bi; rank[bi] = -1e31f;
            wv4[k] = s[bi]; wsum += s[bi];
        }
#pragma unroll
        for (int k = 0; k < 4; k++) {
            topi[t * 4 + k] = sel[k];
            wgt[t * 4 + k] = wv4[k] / wsum;
        }
    }
}

// =====================================================================
// offs: single block; histogram topi -> cnt, prefix -> offs, zero cur
// =====================================================================
__global__ __launch_bounds__(256) void offs_k(const int* __restrict__ topi,
                                              int* cnt, int* offs, int* cur){
    __shared__ int lh[4][12];
    int tid = threadIdx.x, wv = tid >> 6, lane = tid & 63;
    int c[12];
#pragma unroll
    for (int e = 0; e < 12; e++) c[e] = 0;
    for (int i = tid; i < TT * 4; i += 256) {
        int e = topi[i];
#pragma unroll
        for (int q = 0; q < 12; q++) c[q] += (e == q) ? 1 : 0;
    }
#pragma unroll
    for (int e = 0; e < 12; e++) {
        int v = c[e];
#pragma unroll
        for (int d = 1; d < 64; d <<= 1) v += __shfl_xor(v, d, 64);
        if (lane == 0) lh[wv][e] = v;
    }
    __syncthreads();
    if (tid == 0) {
        int a = 0;
        for (int e = 0; e < 12; e++) {
            int tot = lh[0][e] + lh[1][e] + lh[2][e] + lh[3][e];
            cnt[e] = tot; offs[e] = a; a += tot; cur[e] = 0;
        }
        offs[12] = a;
    }
}

// =====================================================================
// scatter: hierarchical — LDS-atomic local ranks, 12 global atomics/block.
// =====================================================================
__global__ __launch_bounds__(256) void scatter_k(const int* __restrict__ topi,
    const float* __restrict__ wgt, const int* __restrict__ offs,
    int* cur, int* tok, float* wgl, int* posm){
    __shared__ int lh[12];
    __shared__ int gb[12];
    int tid = threadIdx.x;
    if (tid < 12) lh[tid] = 0;
    __syncthreads();
    int t = blockIdx.x * 256 + tid;
    int e4[4], lr[4];
#pragma unroll
    for (int k = 0; k < 4; k++) {
        e4[k] = topi[t * 4 + k];
        lr[k] = atomicAdd(&lh[e4[k]], 1);
    }
    __syncthreads();
    if (tid < 12) gb[tid] = atomicAdd(&cur[tid], lh[tid]);
    __syncthreads();
#pragma unroll
    for (int k = 0; k < 4; k++) {
        int pos = offs[e4[k]] + gb[e4[k]] + lr[k];
        tok[pos] = t;
        wgl[pos] = wgt[t * 4 + k];
        posm[t * 4 + k] = pos;
    }
}

// =====================================================================
// final: out = first + shared(bf16) + sum_k wgl*EO   (deterministic gather)
// =====================================================================
__global__ void final_k(const float* __restrict__ first, const u16* __restrict__ so,
    const u16* __restrict__ eo, const int* __restrict__ posm, const float* __restrict__ wgl,
    float* out){
    int idx = blockIdx.x * 256 + threadIdx.x; // t*512 + d4
    int d4 = idx & 511, t = idx >> 9;
    int d = d4 * 4;
    const float* fp = first + (long long)t * DD + d;
    const u16* sp = so + (long long)t * DD + d;
    float r0 = fp[0] + bf16_to_f32(sp[0]);
    float r1 = fp[1] + bf16_to_f32(sp[1]);
    float r2 = fp[2] + bf16_to_f32(sp[2]);
    float r3 = fp[3] + bf16_to_f32(sp[3]);
#pragma unroll
    for (int k = 0; k < 4; k++) {
        int pos = posm[t * 4 + k];
        float wv = wgl[pos];
        const u16* ep = eo + (long long)pos * DD + d;
        r0 += wv * bf16_to_f32(ep[0]);
        r1 += wv * bf16_to_f32(ep[1]);
        r2 += wv * bf16_to_f32(ep[2]);
        r3 += wv * bf16_to_f32(ep[3]);
    }
    float4 res = {r0, r1, r2, r3};
    *(float4*)(out + (long long)t * DD + d) = res;
}

// =====================================================================
// host launch
// =====================================================================
extern "C" void kernel_launch(void* const* d_in, const int* in_sizes, int n_in,
                              void* d_out, int out_size, void* d_ws, size_t ws_size,
                              hipStream_t stream)
{
    const float* x       = (const float*)d_in[0];
    const float* wq      = (const float*)d_in[1];
    const float* wkv_a   = (const float*)d_in[2];
    const float* kvnw    = (const float*)d_in[3];
    const float* wkv_b   = (const float*)d_in[4];
    const float* wo      = (const float*)d_in[5];
    const float* norm_w  = (const float*)d_in[6];
    const float* gate_w  = (const float*)d_in[7];
    const float* gate_b  = (const float*)d_in[8];
    const float* w1      = (const float*)d_in[9];
    const float* w2      = (const float*)d_in[10];
    const float* w3      = (const float*)d_in[11];
    const float* ws1     = (const float*)d_in[12];
    const float* ws2     = (const float*)d_in[13];
    const float* ws3     = (const float*)d_in[14];
    const int*   startp  = (const int*)d_in[16];
    char* ws = (char*)d_ws;

    // ---------- workspace arena (total 141,557,760 bytes) ----------
    const size_t O_COS = 0, O_SIN = 131072, O_KPEH = 262144, O_KPEL = 524288;
    const size_t O_TOPI = 786432, O_WGT = 819200, O_TOK = 851968, O_WGL = 884736, O_POSM = 917504;
    const size_t O_CNT = 950272, O_OFFS = 950336, O_CUR = 950400;
    const size_t O_WB = 1048576;           // weight staging, 30,408,704 bytes (reused)
    const size_t B2 = 31457280;
    const size_t O_H    = B2,             O_HLO  = B2 + 8388608;
    const size_t O_Q    = B2 + 16777216,  O_QLO  = B2 + 29360128;
    const size_t O_KVF  = B2 + 41943040;
    const size_t O_LATH = B2 + 46661632,  O_LATL = B2 + 48758784;
    const size_t O_KVBH = B2 + 50855936,  O_KVBL = B2 + 67633152;
    const size_t O_VTH  = B2,             O_VTL  = B2 + 8388608;
    const size_t O_OH   = B2 + 84410368,  O_OL   = B2 + 92798976;
    const size_t O_FIRST= B2 + 16777216;
    const size_t O_TBF  = B2;
    const size_t O_H1   = B2 + 33554432;
    const size_t O_EO   = B2 + 56623104;
    const size_t O_SH1  = B2 + 90177536;
    const size_t O_SO   = B2 + 101711872;

    float* cosT = (float*)(ws + O_COS);  float* sinT = (float*)(ws + O_SIN);
    u16* kpeh = (u16*)(ws + O_KPEH);     u16* kpel = (u16*)(ws + O_KPEL);
    int* topi = (int*)(ws + O_TOPI);     float* wgt = (float*)(ws + O_WGT);
    int* tok = (int*)(ws + O_TOK);       float* wgl = (float*)(ws + O_WGL);
    int* posm = (int*)(ws + O_POSM);
    int* cntp = (int*)(ws + O_CNT); int* offsp = (int*)(ws + O_OFFS); int* curp = (int*)(ws + O_CUR);
    u16* WB   = (u16*)(ws + O_WB);
    u16* hhi = (u16*)(ws + O_H);    u16* hlo = (u16*)(ws + O_HLO);
    u16* qhp = (u16*)(ws + O_Q);    u16* qlp = (u16*)(ws + O_QLO);
    float* kvf = (float*)(ws + O_KVF);
    u16* lath = (u16*)(ws + O_LATH); u16* latl = (u16*)(ws + O_LATL);
    u16* kvbh = (u16*)(ws + O_KVBH); u16* kvbl = (u16*)(ws + O_KVBL);
    u16* vth = (u16*)(ws + O_VTH);  u16* vtl = (u16*)(ws + O_VTL);
    u16* oh  = (u16*)(ws + O_OH);   u16* ol  = (u16*)(ws + O_OL);
    float* first = (float*)(ws + O_FIRST);
    u16* tbf = (u16*)(ws + O_TBF);
    u16* h1buf = (u16*)(ws + O_H1); u16* eo = (u16*)(ws + O_EO);
    u16* sh1 = (u16*)(ws + O_SH1);  u16* sobuf = (u16*)(ws + O_SO);
    u16* sh3 = (u16*)(ws + O_H1);   // temp during shared phase (h1buf not yet live)

    costab_k<<<128, 256, 0, stream>>>(startp, cosT, sinT);
    rms_k<0><<<TT, 256, 0, stream>>>(x, norm_w, hhi, hlo);

    // ---- merged q|kv = h @ [wq | wkv_a] (precise 64x128 3-deep) ----
    cvtT_k<1><<<dim3(48, 32, 1), 256, 0, stream>>>(wq, 0, WB, WB + 7602176, 0, 2048, 3072);
    cvtT_k<1><<<dim3(10, 32, 1), 256, 0, stream>>>(wkv_a, 0, WB + 6291456, WB + 13893632, 0, 2048, 576);
    gemmp3_k<EPI_QKV><<<dim3(32, 32, 1), 256, 0, stream>>>(
        hhi, hlo, 2048, WB, WB + 7602176, 2048, 3712, 2048,
        qhp, qlp, 3072, kvf, cosT, sinT);
    kvprep_k<<<TT, 256, 0, stream>>>(kvf, kvnw, cosT, sinT, lath, latl, kpeh, kpel);

    // ---- kvb = kv_lat @ wkv_b ---- (precise 64x128 3-deep)
    cvtT_k<1><<<dim3(64, 8, 1), 256, 0, stream>>>(wkv_b, 0, WB, WB + 2097152, 0, 512, 4096);
    gemmp3_k<EPI_F16PAIR><<<dim3(32, 32, 1), 256, 0, stream>>>(
        lath, latl, 512, WB, WB + 2097152, 2048, 4096, 512,
        kvbh, kvbl, 4096, nullptr, nullptr, nullptr);

    vtprep_k<<<dim3(32, 16, 2), 256, 0, stream>>>(kvbh, kvbl, vth, vtl);
    attn_k<<<dim3(16, 32, 1), 256, 0, stream>>>(qhp, qlp, kvbh, kvbl, kpeh, kpel, vth, vtl, oh, ol);

    // ---- first = o @ wo + x ---- (precise 64x128 3-deep)
    cvtT_k<1><<<dim3(32, 32, 1), 256, 0, stream>>>(wo, 0, WB, WB + 4194304, 0, 2048, 2048);
    gemmp3_k<EPI_RES><<<dim3(16, 32, 1), 256, 0, stream>>>(
        oh, ol, 2048, WB, WB + 4194304, 2048, 2048, 2048,
        first, nullptr, 2048, x, nullptr, nullptr);

    rms_k<1><<<TT, 256, 0, stream>>>(first, norm_w, tbf, nullptr);
    gate_k<<<512, 256, 0, stream>>>(first, norm_w, gate_w, gate_b, topi, wgt);
    offs_k<<<1, 256, 0, stream>>>(topi, cntp, offsp, curp);
    scatter_k<<<8, 256, 0, stream>>>(topi, wgt, offsp, curp, tok, wgl, posm);

    // ---- shared expert (fused ws1||ws3; sh3 borrows h1buf) ----
    const long long SW = (long long)2816 * 2048;
    cvtT_k<0><<<dim3(44, 32, 1), 256, 0, stream>>>(ws1, 0, WB, nullptr, 0, 2048, 2816);
    cvtT_k<0><<<dim3(44, 32, 1), 256, 0, stream>>>(ws3, 0, WB + SW, nullptr, 0, 2048, 2816);
    gemm3_k<EPI_BF16, false><<<dim3(24, 32, 2), 256, 0, stream>>>(
        tbf, 2048, WB, SW, 2048, 2816, 2048,
        nullptr, nullptr, nullptr, 0, sh1, sh3, 2816, nullptr, 1);
    silumul_k<<<2816, 256, 0, stream>>>(sh1, sh3, (long long)2048 * 2816);
    cvtT_k<0><<<dim3(32, 44, 1), 256, 0, stream>>>(ws2, 0, WB, nullptr, 0, 2816, 2048);
    gemm3_k<EPI_BF16, false><<<dim3(16, 32, 1), 256, 0, stream>>>(
        sh1, 2816, WB, 0, 2048, 2048, 2816,
        nullptr, nullptr, nullptr, 0, sobuf, nullptr, 2048, nullptr, 0);

    // ---- routed experts, groups of 4 (weight staging reuses WB) ----
    const long long EW = (long long)2048 * 1408;
    for (int g = 0; g < 3; ++g) {
        cvtT_k<0><<<dim3(22, 32, 4), 256, 0, stream>>>(w1 + (long long)g * 4 * EW, EW, WB, nullptr, EW, 2048, 1408);
        gemm3_k<EPI_BF16, true><<<dim3(16, 32, 4), 256, 0, stream>>>(
            tbf, 2048, WB, EW, 2048, 1408, 2048,
            offsp, cntp, tok, 4 * g, h1buf, nullptr, 1408, nullptr, 0);
        cvtT_k<0><<<dim3(22, 32, 4), 256, 0, stream>>>(w3 + (long long)g * 4 * EW, EW, WB, nullptr, EW, 2048, 1408);
        gemm3_k<EPI_SILUMUL, true><<<dim3(16, 32, 4), 256, 0, stream>>>(
            tbf, 2048, WB, EW, 2048, 1408, 2048,
            offsp, cntp, tok, 4 * g, h1buf, nullptr, 1408, h1buf, 0);
        cvtT_k<0><<<dim3(32, 22, 4), 256, 0, stream>>>(w2 + (long long)g * 4 * EW, EW, WB, nullptr, EW, 1408, 2048);
        gemm3_k<EPI_BF16, false><<<dim3(16, 32, 4), 256, 0, stream>>>(
            h1buf, 1408, WB, EW, 2048, 2048, 1408,
            offsp, cntp, nullptr, 4 * g, eo, nullptr, 2048, nullptr, 0);
    }

    final_k<<<4096, 256, 0, stream>>>(first, sobuf, eo, posm, wgl, (float*)d_out);
}

// Round 16
// 1163.067 us; speedup vs baseline: 1.0331x; 1.0331x over previous
//
#include <hip/hip_runtime.h>
#include <math.h>

// ---------- types ----------
typedef unsigned short u16;
typedef __attribute__((ext_vector_type(8))) short short8;     // 8x16-bit raw (bf16 bits)
typedef __attribute__((ext_vector_type(8))) _Float16 half8;   // 8x fp16
typedef __attribute__((ext_vector_type(4))) float f32x4;

__device__ inline u16 f32_to_bf16_rne(float f){
    unsigned int u = __float_as_uint(f);
    unsigned int r = (u + 0x7FFFu + ((u >> 16) & 1u)) >> 16;
    return (u16)r;
}
__device__ inline float bf16_to_f32(u16 h){ return __uint_as_float(((unsigned int)h) << 16); }
__device__ inline u16 h2b(_Float16 h){ union { _Float16 f; u16 u; } x; x.f = h; return x.u; }

__device__ __forceinline__ void glds16(const void* g, void* l){
    __builtin_amdgcn_global_load_lds((const __attribute__((address_space(1))) void*)g,
                                     (__attribute__((address_space(3))) void*)l, 16, 0, 0);
}
#define WAIT_VM0()  { asm volatile("s_waitcnt vmcnt(0)" ::: "memory"); __builtin_amdgcn_sched_barrier(0); }
#define WAIT_VM3()  { asm volatile("s_waitcnt vmcnt(3)" ::: "memory"); __builtin_amdgcn_sched_barrier(0); }
#define WAIT_VM6()  { asm volatile("s_waitcnt vmcnt(6)" ::: "memory"); __builtin_amdgcn_sched_barrier(0); }
#define WAIT_LGKM0() { asm volatile("s_waitcnt lgkmcnt(0)" ::: "memory"); __builtin_amdgcn_sched_barrier(0); }
#define RAW_BAR()   { __builtin_amdgcn_s_barrier(); __builtin_amdgcn_sched_barrier(0); }

// ---------- constants ----------
#define TT 2048      // tokens
#define DD 2048      // model dim
#define SS 1024      // seq len
#define NH 16        // heads

#define EPI_F32     0
#define EPI_BF16    1
#define EPI_RES     2
#define EPI_SILUMUL 3
#define EPI_F16PAIR 4
#define EPI_QROPE   5
#define EPI_QKV     6

// =====================================================================
// Transpose-convert: W[K][N] f32 -> WT[N][K] 16-bit planes (zero-pad rows
// n >= Nsrc). PAIR=1: fp16 hi/lo planes; PAIR=0: bf16 single plane.
// grid: (Npad/64, K/64, E)
// =====================================================================
template<int PAIR>
__global__ __launch_bounds__(256) void cvtT_k(const float* __restrict__ W, long long wstr,
        u16* __restrict__ WTh, u16* __restrict__ WTl, long long tstr, int K, int Nsrc){
    __shared__ float L[64][65];
    int e = blockIdx.z;
    const float* Wp = W + (long long)e * wstr;
    int k0 = blockIdx.y * 64, n0 = blockIdx.x * 64;
    int tid = threadIdx.x;
#pragma unroll
    for (int it = 0; it < 4; ++it) {
        int r = (tid >> 4) + it * 16, cc = (tid & 15) * 4;
        int col = n0 + cc;
        float4 v = {0.f, 0.f, 0.f, 0.f};
        if (col + 3 < Nsrc) v = *(const float4*)(Wp + (long long)(k0 + r) * Nsrc + col);
        else {
            const float* p = Wp + (long long)(k0 + r) * Nsrc;
            float tmp[4] = {0.f, 0.f, 0.f, 0.f};
#pragma unroll
            for (int q2 = 0; q2 < 4; q2++) if (col + q2 < Nsrc) tmp[q2] = p[col + q2];
            v.x = tmp[0]; v.y = tmp[1]; v.z = tmp[2]; v.w = tmp[3];
        }
        L[r][cc] = v.x; L[r][cc+1] = v.y; L[r][cc+2] = v.z; L[r][cc+3] = v.w;
    }
    __syncthreads();
#pragma unroll
    for (int it = 0; it < 2; ++it) {
        int idx = it * 256 + tid; int n = idx >> 3, kc = (idx & 7) * 8;
        u16 hi[8], lo[8];
#pragma unroll
        for (int u = 0; u < 8; ++u) {
            float v = L[kc + u][n];
            if (PAIR) { _Float16 h = (_Float16)v; hi[u] = h2b(h); lo[u] = h2b((_Float16)(v - (float)h)); }
            else hi[u] = f32_to_bf16_rne(v);
        }
        long long o = (long long)e * tstr + (long long)(n0 + n) * K + k0 + kc;
        *(short8*)(WTh + o) = *(short8*)hi;
        if (PAIR) *(short8*)(WTl + o) = *(short8*)lo;
    }
}

// =====================================================================
// PREC 128x128 MFMA GEMM (split-fp16, 3 MFMA/term), 2-phase pipelined
// (double-buffered LDS via glds, raw barriers, counted waits).
// EPI_QKV: merged wq+wkv_a dispatch — n0<3072 -> roped q f16-pair
// (ldc=3072); n0>=3072 -> f32 kv rows into aux (ld 576, cols<3648).
// =====================================================================
template<int EPI, bool PREC, bool AGLDS>
__global__ __launch_bounds__(256) void gemm_k(
    const u16* __restrict__ A0, const u16* __restrict__ A1, int lda,
    const u16* __restrict__ BTh, const u16* __restrict__ BTl, long long btstr,
    int M, int N, int K,
    const int* offs, const int* cnt, const int* gather, int ebase,
    void* C0, void* C1, int ldc,
    const void* aux, const float* __restrict__ cosT, const float* __restrict__ sinT,
    int zsplit)
{
    __shared__ u16 AsH[2][4096];
    __shared__ u16 AsL[PREC ? 2 : 1][PREC ? 4096 : 8];
    __shared__ u16 BsH[2][4096];
    __shared__ u16 BsL[PREC ? 2 : 1][PREC ? 4096 : 8];

    int tid  = threadIdx.x;
    int lane = tid & 63;
    int wv   = tid >> 6;
    int wm = (wv >> 1) * 64, wn = (wv & 1) * 64;

    int Lid = blockIdx.y * gridDim.x + blockIdx.x;
    int jj  = Lid >> 3;
    int yb  = jj % gridDim.y;
    int nb  = (Lid & 7) + ((jj / gridDim.y) << 3);
    int n0 = nb * 128;
    if (n0 >= N) return;

    int zz   = blockIdx.z;
    int e    = ebase + ((zsplit > 0 && zz >= zsplit) ? (zz - zsplit) : zz);
    int base = offs ? offs[e] : 0;
    int mc   = cnt ? cnt[e] : M;
    int m0   = yb * 128;
    if (m0 >= mc) return;
    const u16* Bh = BTh + (long long)zz * btstr;
    const u16* Bl = PREC ? (BTl + (long long)zz * btstr) : (const u16*)nullptr;
    void* Cw = (zsplit > 0 && zz >= zsplit) ? C1 : C0;

    int rr_ = tid >> 2, s4 = tid & 3;
    long long arow0 = -1, arow1 = -1;
    if (!AGLDS) {
        if (m0 + rr_ < mc)      arow0 = gather ? (long long)gather[base + m0 + rr_]      : (long long)(base + m0 + rr_);
        if (m0 + rr_ + 64 < mc) arow1 = gather ? (long long)gather[base + m0 + rr_ + 64] : (long long)(base + m0 + rr_ + 64);
    }

    f32x4 acc[4][4];
#pragma unroll
    for (int i = 0; i < 4; i++)
#pragma unroll
        for (int j = 0; j < 4; j++) { f32x4 z = {0.f,0.f,0.f,0.f}; acc[i][j] = z; }

    short8 zer = {0,0,0,0,0,0,0,0};
    short8 a0h = zer, a1h = zer, a0l = zer, a1l = zer;

    int gr0 = wv * 16 + (lane >> 2);
    int gsl = lane & 3;

#define STAGE_GL(PB, KT)                                                         \
    {                                                                            \
        _Pragma("unroll")                                                        \
        for (int it = 0; it < 2; ++it) {                                         \
            int r = it * 64 + gr0;                                               \
            int s = gsl ^ ((r >> 1) & 3);                                        \
            glds16(Bh + (long long)(n0 + r) * K + (KT) + s * 8,                  \
                   (char*)&BsH[PB][0] + it * 4096 + wv * 1024);                  \
            if (PREC)                                                            \
                glds16(Bl + (long long)(n0 + r) * K + (KT) + s * 8,              \
                       (char*)&BsL[PB][0] + it * 4096 + wv * 1024);              \
            if (AGLDS) {                                                         \
                glds16(A0 + (long long)(base + m0 + r) * lda + (KT) + s * 8,     \
                       (char*)&AsH[PB][0] + it * 4096 + wv * 1024);              \
                if (PREC)                                                        \
                    glds16(A1 + (long long)(base + m0 + r) * lda + (KT) + s * 8, \
                           (char*)&AsL[PB][0] + it * 4096 + wv * 1024);          \
            }                                                                    \
        }                                                                        \
        if (!AGLDS) {                                                            \
            a0h = (arow0 >= 0) ? *(const short8*)(A0 + arow0 * lda + (KT) + s4 * 8) : zer; \
            a1h = (arow1 >= 0) ? *(const short8*)(A0 + arow1 * lda + (KT) + s4 * 8) : zer; \
            if (PREC) {                                                          \
                a0l = (arow0 >= 0) ? *(const short8*)(A1 + arow0 * lda + (KT) + s4 * 8) : zer; \
                a1l = (arow1 >= 0) ? *(const short8*)(A1 + arow1 * lda + (KT) + s4 * 8) : zer; \
            }                                                                    \
        }                                                                        \
    }

    int pb = 0;
    STAGE_GL(0, 0);
    for (int kt = 0; kt < K; kt += 32) {
        WAIT_VM0();
        if (!AGLDS) {
            int d0 = rr_ * 64 + 16 * (s4 ^ ((rr_ >> 1) & 3));
            int r1w = rr_ + 64;
            int d1 = r1w * 64 + 16 * (s4 ^ ((r1w >> 1) & 3));
            *(short8*)((char*)&AsH[pb][0] + d0) = a0h;
            *(short8*)((char*)&AsH[pb][0] + d1) = a1h;
            if (PREC) {
                *(short8*)((char*)&AsL[pb][0] + d0) = a0l;
                *(short8*)((char*)&AsL[pb][0] + d1) = a1l;
            }
            WAIT_LGKM0();
        }
        RAW_BAR();
        if (kt + 32 < K) { STAGE_GL(pb ^ 1, kt + 32); }
        if (PREC) {
            half8 ah[4], al[4];
#pragma unroll
            for (int i = 0; i < 4; i++) {
                int ra = wm + i * 16 + (lane & 15);
                int off = ra * 64 + 16 * ((lane >> 4) ^ ((ra >> 1) & 3));
                ah[i] = *(const half8*)((const char*)&AsH[pb][0] + off);
                al[i] = *(const half8*)((const char*)&AsL[pb][0] + off);
            }
#pragma unroll
            for (int j = 0; j < 4; j++) {
                int rb = wn + j * 16 + (lane & 15);
                int off = rb * 64 + 16 * ((lane >> 4) ^ ((rb >> 1) & 3));
                half8 bh = *(const half8*)((const char*)&BsH[pb][0] + off);
                half8 bl = *(const half8*)((const char*)&BsL[pb][0] + off);
#pragma unroll
                for (int i = 0; i < 4; i++) {
                    acc[i][j] = __builtin_amdgcn_mfma_f32_16x16x32_f16(ah[i], bh, acc[i][j], 0, 0, 0);
                    acc[i][j] = __builtin_amdgcn_mfma_f32_16x16x32_f16(ah[i], bl, acc[i][j], 0, 0, 0);
                    acc[i][j] = __builtin_amdgcn_mfma_f32_16x16x32_f16(al[i], bh, acc[i][j], 0, 0, 0);
                }
            }
        } else {
            short8 af[4];
#pragma unroll
            for (int i = 0; i < 4; i++) {
                int ra = wm + i * 16 + (lane & 15);
                af[i] = *(const short8*)((const char*)&AsH[pb][0] + ra * 64 + 16 * ((lane >> 4) ^ ((ra >> 1) & 3)));
            }
#pragma unroll
            for (int j = 0; j < 4; j++) {
                int rb = wn + j * 16 + (lane & 15);
                short8 bfr = *(const short8*)((const char*)&BsH[pb][0] + rb * 64 + 16 * ((lane >> 4) ^ ((rb >> 1) & 3)));
#pragma unroll
                for (int i = 0; i < 4; i++)
                    acc[i][j] = __builtin_amdgcn_mfma_f32_16x16x32_bf16(af[i], bfr, acc[i][j], 0, 0, 0);
            }
        }
        pb ^= 1;
    }
#undef STAGE_GL

    // ---- epilogue ----
    if (EPI == EPI_QROPE || (EPI == EPI_QKV && n0 < 3072)) {
#pragma unroll
        for (int i = 0; i < 4; i++) {
            int rr0 = m0 + wm + i * 16 + ((lane >> 4) << 2);
#pragma unroll
            for (int j = 0; j < 4; j++) {
                int col = n0 + wn + j * 16 + (lane & 15);
                int hd = col % 192;
#pragma unroll
                for (int r = 0; r < 4; r++) {
                    int rr = rr0 + r;
                    float v = acc[i][j][r];
                    float pv = __shfl_xor(v, 1);
                    float outv = v;
                    if (hd >= 128) {
                        int s = rr & (SS - 1);
                        int pi2 = (hd - 128) >> 1;
                        float cc_ = cosT[s * 32 + pi2], sn_ = sinT[s * 32 + pi2];
                        bool odd = col & 1;
                        float a0 = odd ? pv : v, a1 = odd ? v : pv;
                        outv = odd ? (a0 * sn_ + a1 * cc_) : (a0 * cc_ - a1 * sn_);
                    }
                    long long cidx = (long long)rr * ldc + col;
                    _Float16 hh = (_Float16)outv;
                    ((u16*)C0)[cidx] = h2b(hh);
                    ((u16*)C1)[cidx] = h2b((_Float16)(outv - (float)hh));
                }
            }
        }
    } else if (EPI == EPI_QKV) {
        float* kvo = (float*)aux;
#pragma unroll
        for (int i = 0; i < 4; i++) {
            int rr0 = m0 + wm + i * 16 + ((lane >> 4) << 2);
#pragma unroll
            for (int j = 0; j < 4; j++) {
                int col = n0 + wn + j * 16 + (lane & 15);
                if (col >= 3648) continue;
#pragma unroll
                for (int r = 0; r < 4; r++) {
                    int rr = rr0 + r;
                    kvo[(long long)rr * 576 + (col - 3072)] = acc[i][j][r];
                }
            }
        }
    } else {
#pragma unroll
        for (int i = 0; i < 4; i++) {
            int rbase = m0 + wm + i * 16 + ((lane >> 4) << 2);
#pragma unroll
            for (int j = 0; j < 4; j++) {
                int col = n0 + wn + j * 16 + (lane & 15);
                if (col >= N) continue;
#pragma unroll
                for (int r = 0; r < 4; r++) {
                    int rr = rbase + r;
                    if (rr >= mc) continue;
                    long long cidx = (long long)(base + rr) * ldc + col;
                    float v = acc[i][j][r];
                    if (EPI == EPI_F32)      ((float*)C0)[cidx] = v;
                    else if (EPI == EPI_BF16) ((u16*)Cw)[cidx] = f32_to_bf16_rne(v);
                    else if (EPI == EPI_RES)  ((float*)C0)[cidx] = v + ((const float*)aux)[cidx];
                    else if (EPI == EPI_SILUMUL) {
                        float h1v = bf16_to_f32(((const u16*)aux)[cidx]);
                        float g = h1v / (1.f + __expf(-h1v)) * v;
                        ((u16*)C0)[cidx] = f32_to_bf16_rne(g);
                    } else { // F16PAIR
                        _Float16 hh = (_Float16)v;
                        ((u16*)C0)[cidx] = h2b(hh);
                        ((u16*)C1)[cidx] = h2b((_Float16)(v - (float)hh));
                    }
                }
            }
        }
    }
}

// =====================================================================
// PREC 64x128 MFMA GEMM (split-fp16), 3-deep glds pipeline (72KB LDS,
// counted vmcnt(6): one 6-load tile in flight across the barrier).
// Waves 2x2, wave tile 32x64, acc 2x4. EPI_RES only (wo GEMM).
// =====================================================================
__global__ __launch_bounds__(256) void gemmp3_k(
    const u16* __restrict__ A0, const u16* __restrict__ A1, int lda,
    const u16* __restrict__ BTh, const u16* __restrict__ BTl,
    int M, int N, int K,
    float* __restrict__ C0, int ldc, const float* __restrict__ aux)
{
    __shared__ u16 AsH[3][2048];   // 64 rows x 64B
    __shared__ u16 AsL[3][2048];
    __shared__ u16 BsH[3][4096];   // 128 rows x 64B
    __shared__ u16 BsL[3][4096];

    int tid  = threadIdx.x;
    int lane = tid & 63;
    int wv   = tid >> 6;
    int wm = (wv >> 1) * 32, wn = (wv & 1) * 64;

    int Lid = blockIdx.y * gridDim.x + blockIdx.x;
    int jj  = Lid >> 3;
    int yb  = jj % gridDim.y;
    int nb  = (Lid & 7) + ((jj / gridDim.y) << 3);
    int n0 = nb * 128;
    if (n0 >= N) return;
    int m0 = yb * 64;
    if (m0 >= M) return;

    // per-lane glds source offsets (fixed across K)
    int rr = tid >> 2;                 // 0..63
    int sl4 = tid & 3;
    int sA = sl4 ^ ((rr >> 1) & 3);
    int rb1 = rr + 64;
    int sB1 = sl4 ^ ((rb1 >> 1) & 3);
    long long aro = (long long)(m0 + rr) * lda + sA * 8;
    long long bro0 = (long long)(n0 + rr) * K + sA * 8;
    long long bro1 = (long long)(n0 + rb1) * K + sB1 * 8;

    f32x4 acc[2][4];
#pragma unroll
    for (int i = 0; i < 2; i++)
#pragma unroll
        for (int j = 0; j < 4; j++) { f32x4 z = {0.f,0.f,0.f,0.f}; acc[i][j] = z; }

#define STGP(PB, KT)                                                        \
    {                                                                       \
        glds16(BTh + bro0 + (KT), (char*)&BsH[PB][0] + wv * 1024);          \
        glds16(BTh + bro1 + (KT), (char*)&BsH[PB][0] + 4096 + wv * 1024);   \
        glds16(BTl + bro0 + (KT), (char*)&BsL[PB][0] + wv * 1024);          \
        glds16(BTl + bro1 + (KT), (char*)&BsL[PB][0] + 4096 + wv * 1024);   \
        glds16(A0 + aro + (KT),  (char*)&AsH[PB][0] + wv * 1024);           \
        glds16(A1 + aro + (KT),  (char*)&AsL[PB][0] + wv * 1024);           \
    }

    int nst = K >> 5;
    STGP(0, 0);
    if (nst > 1) STGP(1, 32);
    for (int t = 0; t < nst; ++t) {
        if (t + 1 < nst) { WAIT_VM6(); }   // tile t landed; tile t+1 (6 loads) in flight
        else            { WAIT_VM0(); }
        RAW_BAR();
        if (t + 2 < nst) { int p2 = (t + 2) % 3; STGP(p2, (t + 2) * 32); }
        int pb = t % 3;
        half8 ah[2], al[2];
#pragma unroll
        for (int i = 0; i < 2; i++) {
            int ra = wm + i * 16 + (lane & 15);
            int off = ra * 64 + 16 * ((lane >> 4) ^ ((ra >> 1) & 3));
            ah[i] = *(const half8*)((const char*)&AsH[pb][0] + off);
            al[i] = *(const half8*)((const char*)&AsL[pb][0] + off);
        }
#pragma unroll
        for (int j = 0; j < 4; j++) {
            int rb = wn + j * 16 + (lane & 15);
            int off = rb * 64 + 16 * ((lane >> 4) ^ ((rb >> 1) & 3));
            half8 bh = *(const half8*)((const char*)&BsH[pb][0] + off);
            half8 bl = *(const half8*)((const char*)&BsL[pb][0] + off);
#pragma unroll
            for (int i = 0; i < 2; i++) {
                acc[i][j] = __builtin_amdgcn_mfma_f32_16x16x32_f16(ah[i], bh, acc[i][j], 0, 0, 0);
                acc[i][j] = __builtin_amdgcn_mfma_f32_16x16x32_f16(ah[i], bl, acc[i][j], 0, 0, 0);
                acc[i][j] = __builtin_amdgcn_mfma_f32_16x16x32_f16(al[i], bh, acc[i][j], 0, 0, 0);
            }
        }
    }
#undef STGP

    // ---- epilogue: C0 = acc + aux (f32 residual) ----
#pragma unroll
    for (int i = 0; i < 2; i++) {
        int rbase = m0 + wm + i * 16 + ((lane >> 4) << 2);
#pragma unroll
        for (int j = 0; j < 4; j++) {
            int col = n0 + wn + j * 16 + (lane & 15);
            if (col >= N) continue;
#pragma unroll
            for (int r = 0; r < 4; r++) {
                int rr2 = rbase + r;
                if (rr2 >= M) continue;
                long long cidx = (long long)rr2 * ldc + col;
                C0[cidx] = acc[i][j][r] + aux[cidx];
            }
        }
    }
}

// =====================================================================
// bf16 64x128 MFMA GEMM (4 waves as 2x2, wave tile 32x64, acc 2x4),
// 3-deep glds pipeline (36KB LDS, counted vmcnt(3)).
// =====================================================================
template<int EPI, bool GATHER>
__global__ __launch_bounds__(256) void gemm3_k(
    const u16* __restrict__ A0, int lda,
    const u16* __restrict__ BTh, long long btstr,
    int M, int N, int K,
    const int* offs, const int* cnt, const int* gather, int ebase,
    void* C0, void* C1, int ldc,
    const void* aux, int zsplit)
{
    __shared__ u16 As[3][2048];   // 64 rows x 64B
    __shared__ u16 Bs[3][4096];   // 128 rows x 64B

    int tid  = threadIdx.x;
    int lane = tid & 63;
    int wv   = tid >> 6;
    int wm = (wv >> 1) * 32, wn = (wv & 1) * 64;

    int Lid = blockIdx.y * gridDim.x + blockIdx.x;
    int jj  = Lid >> 3;
    int yb  = jj % gridDim.y;
    int nb  = (Lid & 7) + ((jj / gridDim.y) << 3);
    int n0 = nb * 128;
    if (n0 >= N) return;

    int zz   = blockIdx.z;
    int e    = ebase + ((zsplit > 0 && zz >= zsplit) ? (zz - zsplit) : zz);
    int base = offs ? offs[e] : 0;
    int mc   = cnt ? cnt[e] : M;
    int m0   = yb * 64;
    if (m0 >= mc) return;
    const u16* Bh = BTh + (long long)zz * btstr;
    void* Cw = (zsplit > 0 && zz >= zsplit) ? C1 : C0;

    int rr = tid >> 2;                 // 0..63
    int sl4 = tid & 3;
    int sA = sl4 ^ ((rr >> 1) & 3);
    long long bro0, bro1, aro0;
    {
        int rb1 = rr + 64;
        int sB1 = sl4 ^ ((rb1 >> 1) & 3);
        bro0 = (long long)(n0 + rr) * K + sA * 8;
        bro1 = (long long)(n0 + rb1) * K + sB1 * 8;
        int ar = m0 + rr; ar = (ar < mc) ? ar : (mc - 1);   // clamp; garbage masked at epilogue
        long long ga = GATHER ? (long long)gather[base + ar] : (long long)(base + ar);
        aro0 = ga * (long long)lda + sA * 8;
    }

    f32x4 acc[2][4];
#pragma unroll
    for (int i = 0; i < 2; i++)
#pragma unroll
        for (int j = 0; j < 4; j++) { f32x4 z = {0.f,0.f,0.f,0.f}; acc[i][j] = z; }

#define STG3(PB, KT)                                                        \
    {                                                                       \
        glds16(Bh + bro0 + (KT), (char*)&Bs[PB][0] + wv * 1024);            \
        glds16(Bh + bro1 + (KT), (char*)&Bs[PB][0] + 4096 + wv * 1024);     \
        glds16(A0 + aro0 + (KT), (char*)&As[PB][0] + wv * 1024);            \
    }

    int nst = K >> 5;
    STG3(0, 0);
    if (nst > 1) STG3(1, 32);
    for (int t = 0; t < nst; ++t) {
        if (t + 1 < nst) { WAIT_VM3(); }
        else            { WAIT_VM0(); }
        RAW_BAR();
        if (t + 2 < nst) { int p2 = (t + 2) % 3; STG3(p2, (t + 2) * 32); }
        int pb = t % 3;
        short8 af[2];
#pragma unroll
        for (int i = 0; i < 2; i++) {
            int ra = wm + i * 16 + (lane & 15);
            af[i] = *(const short8*)((const char*)&As[pb][0] + ra * 64 + 16 * ((lane >> 4) ^ ((ra >> 1) & 3)));
        }
#pragma unroll
        for (int j = 0; j < 4; j++) {
            int rb = wn + j * 16 + (lane & 15);
            short8 bfr = *(const short8*)((const char*)&Bs[pb][0] + rb * 64 + 16 * ((lane >> 4) ^ ((rb >> 1) & 3)));
#pragma unroll
            for (int i = 0; i < 2; i++)
                acc[i][j] = __builtin_amdgcn_mfma_f32_16x16x32_bf16(af[i], bfr, acc[i][j], 0, 0, 0);
        }
    }
#undef STG3

    // ---- epilogue ----
#pragma unroll
    for (int i = 0; i < 2; i++) {
        int rbase = m0 + wm + i * 16 + ((lane >> 4) << 2);
#pragma unroll
        for (int j = 0; j < 4; j++) {
            int col = n0 + wn + j * 16 + (lane & 15);
            if (col >= N) continue;
#pragma unroll
            for (int r = 0; r < 4; r++) {
                int rr2 = rbase + r;
                if (rr2 >= mc) continue;
                long long cidx = (long long)(base + rr2) * ldc + col;
                float v = acc[i][j][r];
                if (EPI == EPI_BF16) ((u16*)Cw)[cidx] = f32_to_bf16_rne(v);
                else { // EPI_SILUMUL
                    float h1v = bf16_to_f32(((const u16*)aux)[cidx]);
                    float g = h1v / (1.f + __expf(-h1v)) * v;
                    ((u16*)C0)[cidx] = f32_to_bf16_rne(g);
                }
            }
        }
    }
}

// =====================================================================
// silumul: g = silu(g) * h3 elementwise (bf16), n elements (mult of 8)
// =====================================================================
__global__ __launch_bounds__(256) void silumul_k(u16* __restrict__ g, const u16* __restrict__ h3,
                                                 long long n){
    long long i = ((long long)blockIdx.x * 256 + threadIdx.x) * 8;
    if (i >= n) return;
    short8 a = *(const short8*)(g + i);
    short8 b = *(const short8*)(h3 + i);
    u16 o[8];
#pragma unroll
    for (int u = 0; u < 8; ++u) {
        float x = bf16_to_f32((u16)a[u]);
        float y = bf16_to_f32((u16)b[u]);
        o[u] = f32_to_bf16_rne(x / (1.f + __expf(-x)) * y);
    }
    *(short8*)(g + i) = *(short8*)o;
}

// =====================================================================
// cos/sin table: [S][32]
// =====================================================================
__global__ void costab_k(const int* sp, float* ct, float* st){
    int idx = blockIdx.x * 256 + threadIdx.x;
    if (idx >= SS * 32) return;
    int i = idx & 31, s = idx >> 5;
    float inv = powf(10000.0f, -(float)i / 32.0f);
    float a = (float)(sp[0] + s) * inv;
    ct[idx] = cosf(a);
    st[idx] = sinf(a);
}

// =====================================================================
// rmsnorm: row of 2048 f32 -> MODE 0: fp16 hi/lo planes; MODE 1: bf16
// =====================================================================
template<int MODE>
__global__ __launch_bounds__(256) void rms_k(const float* __restrict__ x, const float* __restrict__ w,
                                             u16* o0, u16* o1){
    int t = blockIdx.x, tid = threadIdx.x;
    const float* row = x + (long long)t * DD;
    float4 v0 = *(const float4*)(row + tid * 4);
    float4 v1 = *(const float4*)(row + 1024 + tid * 4);
    float ss = v0.x*v0.x + v0.y*v0.y + v0.z*v0.z + v0.w*v0.w
             + v1.x*v1.x + v1.y*v1.y + v1.z*v1.z + v1.w*v1.w;
#pragma unroll
    for (int d = 1; d < 64; d <<= 1) ss += __shfl_xor(ss, d, 64);
    __shared__ float red[4];
    if ((tid & 63) == 0) red[tid >> 6] = ss;
    __syncthreads();
    float sc = rsqrtf((red[0] + red[1] + red[2] + red[3]) / (float)DD + 1e-6f);
    float a[8];
    a[0]=v0.x; a[1]=v0.y; a[2]=v0.z; a[3]=v0.w; a[4]=v1.x; a[5]=v1.y; a[6]=v1.z; a[7]=v1.w;
#pragma unroll
    for (int q2 = 0; q2 < 8; q2++) {
        int d = (q2 < 4) ? (tid * 4 + q2) : (1024 + tid * 4 + (q2 - 4));
        float y = a[q2] * sc * w[d];
        if (MODE == 0) {
            _Float16 hh = (_Float16)y;
            o0[(long long)t * DD + d] = h2b(hh);
            o1[(long long)t * DD + d] = h2b((_Float16)(y - (float)hh));
        } else {
            o0[(long long)t * DD + d] = f32_to_bf16_rne(y);
        }
    }
}

// =====================================================================
// kvprep: rmsnorm(kv[:,:512]) -> fp16 pair; rope(kv[:,512:576]) -> fp16 pair
// =====================================================================
__global__ __launch_bounds__(256) void kvprep_k(const float* __restrict__ kv, const float* __restrict__ kw,
    const float* __restrict__ ct, const float* __restrict__ st,
    u16* lath, u16* latl, u16* kpeh, u16* kpel){
    int t = blockIdx.x, tid = threadIdx.x;
    const float* row = kv + (long long)t * 576;
    float x0 = row[tid], x1 = row[256 + tid];
    float ss = x0 * x0 + x1 * x1;
#pragma unroll
    for (int d = 1; d < 64; d <<= 1) ss += __shfl_xor(ss, d, 64);
    __shared__ float red[4];
    if ((tid & 63) == 0) red[tid >> 6] = ss;
    __syncthreads();
    float sc = rsqrtf((red[0] + red[1] + red[2] + red[3]) / 512.f + 1e-6f);
    float y0 = x0 * sc * kw[tid], y1 = x1 * sc * kw[256 + tid];
    _Float16 h0 = (_Float16)y0, h1 = (_Float16)y1;
    lath[(long long)t * 512 + tid] = h2b(h0);
    latl[(long long)t * 512 + tid] = h2b((_Float16)(y0 - (float)h0));
    lath[(long long)t * 512 + 256 + tid] = h2b(h1);
    latl[(long long)t * 512 + 256 + tid] = h2b((_Float16)(y1 - (float)h1));
    if (tid < 32) {
        int s = t & (SS - 1);
        float a0 = row[512 + 2 * tid], a1 = row[513 + 2 * tid];
        float c = ct[s * 32 + tid], sn = st[s * 32 + tid];
        float r0 = a0 * c - a1 * sn, r1 = a0 * sn + a1 * c;
        _Float16 p0 = (_Float16)r0, p1 = (_Float16)r1;
        kpeh[(long long)t * 64 + 2 * tid]     = h2b(p0);
        kpel[(long long)t * 64 + 2 * tid]     = h2b((_Float16)(r0 - (float)p0));
        kpeh[(long long)t * 64 + 2 * tid + 1] = h2b(p1);
        kpel[(long long)t * 64 + 2 * tid + 1] = h2b((_Float16)(r1 - (float)p1));
    }
}

// =====================================================================
// vtprep: v^T planes [BH][128][S] from kvb planes (z selects plane)
// =====================================================================
__global__ __launch_bounds__(256) void vtprep_k(const u16* __restrict__ kvbh, const u16* __restrict__ kvbl,
                                                u16* vth, u16* vtl){
    __shared__ u16 L[64][136];
    int bh = blockIdx.x, st = blockIdx.y, pl = blockIdx.z;
    const u16* src = pl ? kvbl : kvbh;
    u16* dst = pl ? vtl : vth;
    int b = bh >> 4, hh = bh & 15;
    int tid = threadIdx.x;
#pragma unroll
    for (int it = 0; it < 4; ++it) {
        int idx = it * 256 + tid; int sl = idx >> 4, dc = idx & 15;
        long long t = (long long)b * SS + st * 64 + sl;
        *(short8*)&L[sl][dc * 8] = *(const short8*)(src + t * 4096 + hh * 256 + 128 + dc * 8);
    }
    __syncthreads();
#pragma unroll
    for (int it = 0; it < 4; ++it) {
        int idx = it * 256 + tid; int d = idx >> 3, sc = idx & 7;
        short8 v;
#pragma unroll
        for (int u = 0; u < 8; u++) v[u] = (short)L[sc * 8 + u][d];
        *(short8*)(dst + ((long long)bh * 128 + d) * SS + st * 64 + sc * 8) = v;
    }
}

// =====================================================================
// Flash attention, split-fp16, causal. T14 async-staged K/V (reg prefetch
// overlaps compute), per-CU complementary-qi pairing for load balance.
// =====================================================================
__global__ __launch_bounds__(256) void attn_k(
    const u16* __restrict__ qh_, const u16* __restrict__ ql_,
    const u16* __restrict__ kvbh, const u16* __restrict__ kvbl,
    const u16* __restrict__ kpeh, const u16* __restrict__ kpel,
    const u16* __restrict__ vth, const u16* __restrict__ vtl,
    u16* ohi, u16* olo)
{
    __shared__ u16 KsH[32][200], KsL[32][200];
    __shared__ u16 VsH[128][40], VsL[128][40];
    __shared__ u16 PlH[4][16][40], PlL[4][16][40];
    int bx = blockIdx.x, bh = blockIdx.y;
    int qi = (bh & 16) ? bx : (15 - bx);
    int b = bh >> 4, h = bh & 15;
    int tid = threadIdx.x, lane = tid & 63, wv = tid >> 6;
    int q0 = qi * 64;
    const u16* vbh = vth + (long long)bh * 128 * SS;
    const u16* vbl = vtl + (long long)bh * 128 * SS;

    half8 qh[6], ql[6];
    {
        int row = q0 + wv * 16 + (lane & 15);
        const u16* ph = qh_ + (long long)(b * SS + row) * 3072 + h * 192 + (lane >> 4) * 8;
        const u16* pl = ql_ + (long long)(b * SS + row) * 3072 + h * 192 + (lane >> 4) * 8;
#pragma unroll
        for (int ks = 0; ks < 6; ks++) {
            qh[ks] = *(const half8*)(ph + ks * 32);
            ql[ks] = *(const half8*)(pl + ks * 32);
        }
    }
    float mrun[4], lrun[4];
    f32x4 oacc[8];
#pragma unroll
    for (int r = 0; r < 4; r++) { mrun[r] = -1e30f; lrun[r] = 0.f; }
#pragma unroll
    for (int f = 0; f < 8; f++) { f32x4 z = {0.f,0.f,0.f,0.f}; oacc[f] = z; }
    const float scale = 0.07216878364870322f; // 1/sqrt(192)

    short8 kh0, kh1, kh2, kl0, kl1, kl2, vh0, vh1, vl0, vl1;
    int kr0 = tid / 24 + 0,  kc0 = tid % 24;
    int kr1 = (256 + tid) / 24, kc1 = (256 + tid) % 24;
    int kr2 = (512 + tid) / 24, kc2 = (512 + tid) % 24;
    int vr0 = tid >> 2, vc0 = tid & 3;
    int vr1 = (256 + tid) >> 2, vc1 = vc0;

#define ALOAD(T0)                                                                   \
    {                                                                               \
        long long tg0 = (long long)b * SS + (T0);                                   \
        if (kc0 < 16) { kh0 = *(const short8*)(kvbh + (tg0 + kr0) * 4096 + h * 256 + kc0 * 8); \
                        kl0 = *(const short8*)(kvbl + (tg0 + kr0) * 4096 + h * 256 + kc0 * 8); } \
        else          { kh0 = *(const short8*)(kpeh + (tg0 + kr0) * 64 + (kc0 - 16) * 8);      \
                        kl0 = *(const short8*)(kpel + (tg0 + kr0) * 64 + (kc0 - 16) * 8); }    \
        if (kc1 < 16) { kh1 = *(const short8*)(kvbh + (tg0 + kr1) * 4096 + h * 256 + kc1 * 8); \
                        kl1 = *(const short8*)(kvbl + (tg0 + kr1) * 4096 + h * 256 + kc1 * 8); } \
        else          { kh1 = *(const short8*)(kpeh + (tg0 + kr1) * 64 + (kc1 - 16) * 8);      \
                        kl1 = *(const short8*)(kpel + (tg0 + kr1) * 64 + (kc1 - 16) * 8); }    \
        if (kc2 < 16) { kh2 = *(const short8*)(kvbh + (tg0 + kr2) * 4096 + h * 256 + kc2 * 8); \
                        kl2 = *(const short8*)(kvbl + (tg0 + kr2) * 4096 + h * 256 + kc2 * 8); } \
        else          { kh2 = *(const short8*)(kpeh + (tg0 + kr2) * 64 + (kc2 - 16) * 8);      \
                        kl2 = *(const short8*)(kpel + (tg0 + kr2) * 64 + (kc2 - 16) * 8); }    \
        vh0 = *(const short8*)(vbh + (long long)vr0 * SS + (T0) + vc0 * 8);         \
        vl0 = *(const short8*)(vbl + (long long)vr0 * SS + (T0) + vc0 * 8);         \
        vh1 = *(const short8*)(vbh + (long long)vr1 * SS + (T0) + vc1 * 8);         \
        vl1 = *(const short8*)(vbl + (long long)vr1 * SS + (T0) + vc1 * 8);         \
    }

    int ntile = 2 * qi + 2;
    ALOAD(0);
    for (int ti = 0; ti < ntile; ++ti) {
        int t0 = ti * 32;
        WAIT_VM0();
        RAW_BAR();
        *(short8*)&KsH[kr0][kc0 * 8] = kh0; *(short8*)&KsL[kr0][kc0 * 8] = kl0;
        *(short8*)&KsH[kr1][kc1 * 8] = kh1; *(short8*)&KsL[kr1][kc1 * 8] = kl1;
        *(short8*)&KsH[kr2][kc2 * 8] = kh2; *(short8*)&KsL[kr2][kc2 * 8] = kl2;
        *(short8*)&VsH[vr0][vc0 * 8] = vh0; *(short8*)&VsL[vr0][vc0 * 8] = vl0;
        *(short8*)&VsH[vr1][vc1 * 8] = vh1; *(short8*)&VsL[vr1][vc1 * 8] = vl1;
        WAIT_LGKM0();
        RAW_BAR();
        if (ti + 1 < ntile) ALOAD(t0 + 32);
        f32x4 s[2];
#pragma unroll
        for (int nt = 0; nt < 2; ++nt) {
            f32x4 a = {0.f,0.f,0.f,0.f};
#pragma unroll
            for (int ks = 0; ks < 6; ++ks) {
                half8 kh = *(const half8*)&KsH[nt * 16 + (lane & 15)][ks * 32 + (lane >> 4) * 8];
                half8 kl = *(const half8*)&KsL[nt * 16 + (lane & 15)][ks * 32 + (lane >> 4) * 8];
                a = __builtin_amdgcn_mfma_f32_16x16x32_f16(qh[ks], kh, a, 0, 0, 0);
                a = __builtin_amdgcn_mfma_f32_16x16x32_f16(qh[ks], kl, a, 0, 0, 0);
                a = __builtin_amdgcn_mfma_f32_16x16x32_f16(ql[ks], kh, a, 0, 0, 0);
            }
            s[nt] = a;
        }
#pragma unroll
        for (int nt = 0; nt < 2; ++nt)
#pragma unroll
            for (int r = 0; r < 4; ++r) {
                float v = s[nt][r] * scale;
                if (ti >= 2 * qi) {
                    int t = t0 + nt * 16 + (lane & 15);
                    int sq = q0 + wv * 16 + (lane >> 4) * 4 + r;
                    if (t > sq) v = -1e30f;
                }
                s[nt][r] = v;
            }
        float corr[4];
#pragma unroll
        for (int r = 0; r < 4; ++r) {
            float m = fmaxf(s[0][r], s[1][r]);
#pragma unroll
            for (int d = 1; d < 16; d <<= 1) m = fmaxf(m, __shfl_xor(m, d, 64));
            float mn = fmaxf(mrun[r], m);
            corr[r] = __expf(mrun[r] - mn);
            mrun[r] = mn;
        }
        float rs[4] = {0.f, 0.f, 0.f, 0.f};
#pragma unroll
        for (int nt = 0; nt < 2; ++nt)
#pragma unroll
            for (int r = 0; r < 4; ++r) {
                float p = __expf(s[nt][r] - mrun[r]);
                s[nt][r] = p;
                rs[r] += p;
            }
#pragma unroll
        for (int r = 0; r < 4; ++r) {
            float tsum = rs[r];
#pragma unroll
            for (int d = 1; d < 16; d <<= 1) tsum += __shfl_xor(tsum, d, 64);
            lrun[r] = lrun[r] * corr[r] + tsum;
        }
#pragma unroll
        for (int f = 0; f < 8; f++)
#pragma unroll
            for (int r = 0; r < 4; r++) oacc[f][r] *= corr[r];
#pragma unroll
        for (int nt = 0; nt < 2; ++nt)
#pragma unroll
            for (int r = 0; r < 4; ++r) {
                float p = s[nt][r];
                _Float16 ph = (_Float16)p;
                PlH[wv][(lane >> 4) * 4 + r][nt * 16 + (lane & 15)] = h2b(ph);
                PlL[wv][(lane >> 4) * 4 + r][nt * 16 + (lane & 15)] = h2b((_Float16)(p - (float)ph));
            }
        half8 pfh = *(const half8*)&PlH[wv][lane & 15][(lane >> 4) * 8];
        half8 pfl = *(const half8*)&PlL[wv][lane & 15][(lane >> 4) * 8];
#pragma unroll
        for (int f = 0; f < 8; ++f) {
            half8 vh = *(const half8*)&VsH[f * 16 + (lane & 15)][(lane >> 4) * 8];
            half8 vl = *(const half8*)&VsL[f * 16 + (lane & 15)][(lane >> 4) * 8];
            oacc[f] = __builtin_amdgcn_mfma_f32_16x16x32_f16(pfh, vh, oacc[f], 0, 0, 0);
            oacc[f] = __builtin_amdgcn_mfma_f32_16x16x32_f16(pfh, vl, oacc[f], 0, 0, 0);
            oacc[f] = __builtin_amdgcn_mfma_f32_16x16x32_f16(pfl, vh, oacc[f], 0, 0, 0);
        }
    }
#undef ALOAD
#pragma unroll
    for (int f = 0; f < 8; ++f)
#pragma unroll
        for (int r = 0; r < 4; ++r) {
            int sq = q0 + wv * 16 + (lane >> 4) * 4 + r;
            float v = oacc[f][r] / lrun[r];
            _Float16 hh = (_Float16)v;
            long long o = ((long long)(b * SS + sq)) * 2048 + h * 128 + f * 16 + (lane & 15);
            ohi[o] = h2b(hh);
            olo[o] = h2b((_Float16)(v - (float)hh));
        }
}

// =====================================================================
// gate: per-token f32 rmsnorm + 12 dots + sigmoid + top-4 (wave per token)
// =====================================================================
__global__ __launch_bounds__(256) void gate_k(const float* __restrict__ first,
    const float* __restrict__ nw, const float* __restrict__ gw, const float* __restrict__ gb,
    int* topi, float* wgt){
    int wv = threadIdx.x >> 6, lane = threadIdx.x & 63;
    int t = blockIdx.x * 4 + wv;
    const float* row = first + (long long)t * DD;
    float rv[32];
    float ss = 0.f;
#pragma unroll
    for (int it = 0; it < 32; ++it) {
        float v = row[it * 64 + lane];
        rv[it] = v;
        ss += v * v;
    }
#pragma unroll
    for (int d = 1; d < 64; d <<= 1) ss += __shfl_xor(ss, d, 64);
    float sc = rsqrtf(ss / (float)DD + 1e-6f);
    float acc[12];
#pragma unroll
    for (int e = 0; e < 12; e++) acc[e] = 0.f;
#pragma unroll
    for (int it = 0; it < 32; ++it) {
        int i = it * 64 + lane;
        float v = rv[it] * sc * nw[i];
        const float* g = gw + (long long)i * 12;
        float4 g0 = *(const float4*)g;
        float4 g1 = *(const float4*)(g + 4);
        float4 g2 = *(const float4*)(g + 8);
        acc[0] += v * g0.x; acc[1] += v * g0.y; acc[2]  += v * g0.z; acc[3]  += v * g0.w;
        acc[4] += v * g1.x; acc[5] += v * g1.y; acc[6]  += v * g1.z; acc[7]  += v * g1.w;
        acc[8] += v * g2.x; acc[9] += v * g2.y; acc[10] += v * g2.z; acc[11] += v * g2.w;
    }
#pragma unroll
    for (int e = 0; e < 12; e++)
#pragma unroll
        for (int d = 1; d < 64; d <<= 1) acc[e] += __shfl_xor(acc[e], d, 64);
    if (lane == 0) {
        float s[12], rank[12];
#pragma unroll
        for (int e = 0; e < 12; e++) { s[e] = 1.f / (1.f + expf(-acc[e])); rank[e] = s[e] + gb[e]; }
        int sel[4]; float wv4[4]; float wsum = 0.f;
#pragma unroll
        for (int k = 0; k < 4; k++) {
            int bi = 0; float bv = -1e30f;
#pragma unroll
            for (int e = 0; e < 12; e++) if (rank[e] > bv) { bv = rank[e]; bi = e; }
            sel[k] = bi; rank[bi] = -1e31f;
            wv4[k] = s[bi]; wsum += s[bi];
        }
#pragma unroll
        for (int k = 0; k < 4; k++) {
            topi[t * 4 + k] = sel[k];
            wgt[t * 4 + k] = wv4[k] / wsum;
        }
    }
}

// =====================================================================
// offs: single block; histogram topi -> cnt, prefix -> offs, zero cur
// =====================================================================
__global__ __launch_bounds__(256) void offs_k(const int* __restrict__ topi,
                                              int* cnt, int* offs, int* cur){
    __shared__ int lh[4][12];
    int tid = threadIdx.x, wv = tid >> 6, lane = tid & 63;
    int c[12];
#pragma unroll
    for (int e = 0; e < 12; e++) c[e] = 0;
    for (int i = tid; i < TT * 4; i += 256) {
        int e = topi[i];
#pragma unroll
        for (int q = 0; q < 12; q++) c[q] += (e == q) ? 1 : 0;
    }
#pragma unroll
    for (int e = 0; e < 12; e++) {
        int v = c[e];
#pragma unroll
        for (int d = 1; d < 64; d <<= 1) v += __shfl_xor(v, d, 64);
        if (lane == 0) lh[wv][e] = v;
    }
    __syncthreads();
    if (tid == 0) {
        int a = 0;
        for (int e = 0; e < 12; e++) {
            int tot = lh[0][e] + lh[1][e] + lh[2][e] + lh[3][e];
            cnt[e] = tot; offs[e] = a; a += tot; cur[e] = 0;
        }
        offs[12] = a;
    }
}

// =====================================================================
// scatter: hierarchical — LDS-atomic local ranks, 12 global atomics/block.
// =====================================================================
__global__ __launch_bounds__(256) void scatter_k(const int* __restrict__ topi,
    const float* __restrict__ wgt, const int* __restrict__ offs,
    int* cur, int* tok, float* wgl, int* posm){
    __shared__ int lh[12];
    __shared__ int gb[12];
    int tid = threadIdx.x;
    if (tid < 12) lh[tid] = 0;
    __syncthreads();
    int t = blockIdx.x * 256 + tid;
    int e4[4], lr[4];
#pragma unroll
    for (int k = 0; k < 4; k++) {
        e4[k] = topi[t * 4 + k];
        lr[k] = atomicAdd(&lh[e4[k]], 1);
    }
    __syncthreads();
    if (tid < 12) gb[tid] = atomicAdd(&cur[tid], lh[tid]);
    __syncthreads();
#pragma unroll
    for (int k = 0; k < 4; k++) {
        int pos = offs[e4[k]] + gb[e4[k]] + lr[k];
        tok[pos] = t;
        wgl[pos] = wgt[t * 4 + k];
        posm[t * 4 + k] = pos;
    }
}

// =====================================================================
// final: out = first + shared(bf16) + sum_k wgl*EO   (deterministic gather)
// =====================================================================
__global__ void final_k(const float* __restrict__ first, const u16* __restrict__ so,
    const u16* __restrict__ eo, const int* __restrict__ posm, const float* __restrict__ wgl,
    float* out){
    int idx = blockIdx.x * 256 + threadIdx.x; // t*512 + d4
    int d4 = idx & 511, t = idx >> 9;
    int d = d4 * 4;
    const float* fp = first + (long long)t * DD + d;
    const u16* sp = so + (long long)t * DD + d;
    float r0 = fp[0] + bf16_to_f32(sp[0]);
    float r1 = fp[1] + bf16_to_f32(sp[1]);
    float r2 = fp[2] + bf16_to_f32(sp[2]);
    float r3 = fp[3] + bf16_to_f32(sp[3]);
#pragma unroll
    for (int k = 0; k < 4; k++) {
        int pos = posm[t * 4 + k];
        float wv = wgl[pos];
        const u16* ep = eo + (long long)pos * DD + d;
        r0 += wv * bf16_to_f32(ep[0]);
        r1 += wv * bf16_to_f32(ep[1]);
        r2 += wv * bf16_to_f32(ep[2]);
        r3 += wv * bf16_to_f32(ep[3]);
    }
    float4 res = {r0, r1, r2, r3};
    *(float4*)(out + (long long)t * DD + d) = res;
}

// =====================================================================
// host launch
// =====================================================================
extern "C" void kernel_launch(void* const* d_in, const int* in_sizes, int n_in,
                              void* d_out, int out_size, void* d_ws, size_t ws_size,
                              hipStream_t stream)
{
    const float* x       = (const float*)d_in[0];
    const float* wq      = (const float*)d_in[1];
    const float* wkv_a   = (const float*)d_in[2];
    const float* kvnw    = (const float*)d_in[3];
    const float* wkv_b   = (const float*)d_in[4];
    const float* wo      = (const float*)d_in[5];
    const float* norm_w  = (const float*)d_in[6];
    const float* gate_w  = (const float*)d_in[7];
    const float* gate_b  = (const float*)d_in[8];
    const float* w1      = (const float*)d_in[9];
    const float* w2      = (const float*)d_in[10];
    const float* w3      = (const float*)d_in[11];
    const float* ws1     = (const float*)d_in[12];
    const float* ws2     = (const float*)d_in[13];
    const float* ws3     = (const float*)d_in[14];
    const int*   startp  = (const int*)d_in[16];
    char* ws = (char*)d_ws;

    // ---------- workspace arena (total 141,557,760 bytes) ----------
    const size_t O_COS = 0, O_SIN = 131072, O_KPEH = 262144, O_KPEL = 524288;
    const size_t O_TOPI = 786432, O_WGT = 819200, O_TOK = 851968, O_WGL = 884736, O_POSM = 917504;
    const size_t O_CNT = 950272, O_OFFS = 950336, O_CUR = 950400;
    const size_t O_WB = 1048576;           // weight staging, 30,408,704 bytes (reused)
    const size_t B2 = 31457280;
    const size_t O_H    = B2,             O_HLO  = B2 + 8388608;
    const size_t O_Q    = B2 + 16777216,  O_QLO  = B2 + 29360128;
    const size_t O_KVF  = B2 + 41943040;
    const size_t O_LATH = B2 + 46661632,  O_LATL = B2 + 48758784;
    const size_t O_KVBH = B2 + 50855936,  O_KVBL = B2 + 67633152;
    const size_t O_VTH  = B2,             O_VTL  = B2 + 8388608;
    const size_t O_OH   = B2 + 84410368,  O_OL   = B2 + 92798976;
    const size_t O_FIRST= B2 + 16777216;
    const size_t O_TBF  = B2;
    const size_t O_H1   = B2 + 33554432;
    const size_t O_EO   = B2 + 56623104;
    const size_t O_SH1  = B2 + 90177536;
    const size_t O_SO   = B2 + 101711872;

    float* cosT = (float*)(ws + O_COS);  float* sinT = (float*)(ws + O_SIN);
    u16* kpeh = (u16*)(ws + O_KPEH);     u16* kpel = (u16*)(ws + O_KPEL);
    int* topi = (int*)(ws + O_TOPI);     float* wgt = (float*)(ws + O_WGT);
    int* tok = (int*)(ws + O_TOK);       float* wgl = (float*)(ws + O_WGL);
    int* posm = (int*)(ws + O_POSM);
    int* cntp = (int*)(ws + O_CNT); int* offsp = (int*)(ws + O_OFFS); int* curp = (int*)(ws + O_CUR);
    u16* WB   = (u16*)(ws + O_WB);
    u16* hhi = (u16*)(ws + O_H);    u16* hlo = (u16*)(ws + O_HLO);
    u16* qhp = (u16*)(ws + O_Q);    u16* qlp = (u16*)(ws + O_QLO);
    float* kvf = (float*)(ws + O_KVF);
    u16* lath = (u16*)(ws + O_LATH); u16* latl = (u16*)(ws + O_LATL);
    u16* kvbh = (u16*)(ws + O_KVBH); u16* kvbl = (u16*)(ws + O_KVBL);
    u16* vth = (u16*)(ws + O_VTH);  u16* vtl = (u16*)(ws + O_VTL);
    u16* oh  = (u16*)(ws + O_OH);   u16* ol  = (u16*)(ws + O_OL);
    float* first = (float*)(ws + O_FIRST);
    u16* tbf = (u16*)(ws + O_TBF);
    u16* h1buf = (u16*)(ws + O_H1); u16* eo = (u16*)(ws + O_EO);
    u16* sh1 = (u16*)(ws + O_SH1);  u16* sobuf = (u16*)(ws + O_SO);
    u16* sh3 = (u16*)(ws + O_H1);   // temp during shared phase (h1buf not yet live)

    costab_k<<<128, 256, 0, stream>>>(startp, cosT, sinT);
    rms_k<0><<<TT, 256, 0, stream>>>(x, norm_w, hhi, hlo);

    // ---- merged q|kv = h @ [wq | wkv_a] (precise; rope-q + f32-kv epilogue) ----
    cvtT_k<1><<<dim3(48, 32, 1), 256, 0, stream>>>(wq, 0, WB, WB + 7602176, 0, 2048, 3072);
    cvtT_k<1><<<dim3(10, 32, 1), 256, 0, stream>>>(wkv_a, 0, WB + 6291456, WB + 13893632, 0, 2048, 576);
    gemm_k<EPI_QKV, true, true><<<dim3(32, 16, 1), 256, 0, stream>>>(
        hhi, hlo, 2048, WB, WB + 7602176, 0, 2048, 3712, 2048,
        nullptr, nullptr, nullptr, 0, qhp, qlp, 3072, kvf, cosT, sinT, 0);
    kvprep_k<<<TT, 256, 0, stream>>>(kvf, kvnw, cosT, sinT, lath, latl, kpeh, kpel);

    // ---- kvb = kv_lat @ wkv_b ---- (precise)
    cvtT_k<1><<<dim3(64, 8, 1), 256, 0, stream>>>(wkv_b, 0, WB, WB + 2097152, 0, 512, 4096);
    gemm_k<EPI_F16PAIR, true, true><<<dim3(32, 16, 1), 256, 0, stream>>>(
        lath, latl, 512, WB, WB + 2097152, 0, 2048, 4096, 512,
        nullptr, nullptr, nullptr, 0, kvbh, kvbl, 4096, nullptr, nullptr, nullptr, 0);

    vtprep_k<<<dim3(32, 16, 2), 256, 0, stream>>>(kvbh, kvbl, vth, vtl);
    attn_k<<<dim3(16, 32, 1), 256, 0, stream>>>(qhp, qlp, kvbh, kvbl, kpeh, kpel, vth, vtl, oh, ol);

    // ---- first = o @ wo + x ---- (precise, 64x128 3-deep)
    cvtT_k<1><<<dim3(32, 32, 1), 256, 0, stream>>>(wo, 0, WB, WB + 4194304, 0, 2048, 2048);
    gemmp3_k<<<dim3(16, 32, 1), 256, 0, stream>>>(
        oh, ol, 2048, WB, WB + 4194304, 2048, 2048, 2048,
        first, 2048, x);

    rms_k<1><<<TT, 256, 0, stream>>>(first, norm_w, tbf, nullptr);
    gate_k<<<512, 256, 0, stream>>>(first, norm_w, gate_w, gate_b, topi, wgt);
    offs_k<<<1, 256, 0, stream>>>(topi, cntp, offsp, curp);
    scatter_k<<<8, 256, 0, stream>>>(topi, wgt, offsp, curp, tok, wgl, posm);

    // ---- shared expert (fused ws1||ws3; sh3 borrows h1buf) ----
    const long long SW = (long long)2816 * 2048;
    cvtT_k<0><<<dim3(44, 32, 1), 256, 0, stream>>>(ws1, 0, WB, nullptr, 0, 2048, 2816);
    cvtT_k<0><<<dim3(44, 32, 1), 256, 0, stream>>>(ws3, 0, WB + SW, nullptr, 0, 2048, 2816);
    gemm3_k<EPI_BF16, false><<<dim3(24, 32, 2), 256, 0, stream>>>(
        tbf, 2048, WB, SW, 2048, 2816, 2048,
        nullptr, nullptr, nullptr, 0, sh1, sh3, 2816, nullptr, 1);
    silumul_k<<<2816, 256, 0, stream>>>(sh1, sh3, (long long)2048 * 2816);
    cvtT_k<0><<<dim3(32, 44, 1), 256, 0, stream>>>(ws2, 0, WB, nullptr, 0, 2816, 2048);
    gemm3_k<EPI_BF16, false><<<dim3(16, 32, 1), 256, 0, stream>>>(
        sh1, 2816, WB, 0, 2048, 2048, 2816,
        nullptr, nullptr, nullptr, 0, sobuf, nullptr, 2048, nullptr, 0);

    // ---- routed experts, groups of 4 (weight staging reuses WB) ----
    const long long EW = (long long)2048 * 1408;
    for (int g = 0; g < 3; ++g) {
        cvtT_k<0><<<dim3(22, 32, 4), 256, 0, stream>>>(w1 + (long long)g * 4 * EW, EW, WB, nullptr, EW, 2048, 1408);
        gemm3_k<EPI_BF16, true><<<dim3(16, 32, 4), 256, 0, stream>>>(
            tbf, 2048, WB, EW, 2048, 1408, 2048,
            offsp, cntp, tok, 4 * g, h1buf, nullptr, 1408, nullptr, 0);
        cvtT_k<0><<<dim3(22, 32, 4), 256, 0, stream>>>(w3 + (long long)g * 4 * EW, EW, WB, nullptr, EW, 2048, 1408);
        gemm3_k<EPI_SILUMUL, true><<<dim3(16, 32, 4), 256, 0, stream>>>(
            tbf, 2048, WB, EW, 2048, 1408, 2048,
            offsp, cntp, tok, 4 * g, h1buf, nullptr, 1408, h1buf, 0);
        cvtT_k<0><<<dim3(32, 22, 4), 256, 0, stream>>>(w2 + (long long)g * 4 * EW, EW, WB, nullptr, EW, 1408, 2048);
        gemm3_k<EPI_BF16, false><<<dim3(16, 32, 4), 256, 0, stream>>>(
            h1buf, 1408, WB, EW, 2048, 2048, 1408,
            offsp, cntp, nullptr, 4 * g, eo, nullptr, 2048, nullptr, 0);
    }

    final_k<<<4096, 256, 0, stream>>>(first, sobuf, eo, posm, wgl, (float*)d_out);
}